// Round 22
// baseline (1078.308 us; speedup 1.0000x reference)
//
#include <hip/hip_runtime.h>
#include <hip/hip_bf16.h>

// MoE experts MLP: E=8, T=2048, H=2048, F=4096, fp32 in/out.
// Base = r18 measured best (999.1 us). r22 change: PERSISTENT gateup blocks.
// gateup grid (32,8,1); each block loops z over the B=4 experts. At each
// z-boundary the next expert's prologue stages (8 global_load_lds) are issued
// BEFORE the epilogue stores -> load latency hides under epilogue VALU/writes,
// and 3 block-generation launch/retire ramps per dispatch are eliminated
// (gateup was 1024 blocks = 4 sequential generations; down is 256 = 1).
// Boundary sync: rotation continues (cur += NT%3 = +1; staged bufs != last-
// read buf); vmcnt(4) after epilogue forces the 8 boundary loads done (loads
// oldest in FIFO, stores newest); barrier; in-loop counted-vmcnt ledger holds.
// GEMM structure (both kernels): BK=32, 512 thr/8 waves, 3-buffer LDS
// rotation, distance-2 prefetch, counted vmcnt(4) (0 only at tail), 2-phase
// K-step, global_load_lds(16B) pre-swizzled source (conflict-free XOR
// swizzle), setprio, XCD COLUMN grouping, launch_bounds(512,2), B=4.

#define EXPERTS 8
#define TOK 2048
#define HID 2048
#define FFN 4096

#define BKQ 32

typedef float f32x4 __attribute__((ext_vector_type(4)));
typedef __bf16 bf16x8 __attribute__((ext_vector_type(8)));

#if defined(__has_builtin)
#if __has_builtin(__builtin_amdgcn_global_load_lds)
#define HAVE_GLL 1
#endif
#endif

__device__ __forceinline__ void gload_lds16(const __bf16* g, __bf16* l, int lane) {
#ifdef HAVE_GLL
    __builtin_amdgcn_global_load_lds((const __attribute__((address_space(1))) void*)g,
                                     (__attribute__((address_space(3))) void*)l,
                                     16, 0, 0);
#else
    bf16x8 v = *(const bf16x8*)g;
    *(bf16x8*)(l + lane * 8) = v;
#endif
}

// BK=32 rows are 4 octets; swizzle o ^ ((row>>1)&3): conflict-free (measured 0).
__device__ __forceinline__ bf16x8 ldfrag32(const __bf16* s, int row, int fq) {
    return *(const bf16x8*)(s + row * BKQ + ((fq ^ ((row >> 1) & 3)) << 3));
}

// Stage 256x32 bf16 tile (2 gload_lds / thread, 512 threads).
__device__ __forceinline__ void stage256(__bf16* dst, const __bf16* src, size_t ld, int tid) {
    const int w = tid >> 6, l = tid & 63;
    const int ri = l >> 2, o = l & 3;
#pragma unroll
    for (int q = 0; q < 2; ++q) {
        const int row = q * 128 + w * 16 + ri;
        gload_lds16(src + (size_t)row * ld + ((o ^ ((row >> 1) & 3)) << 3),
                    dst + (size_t)(q * 128 + w * 16) * BKQ, l);
    }
}

// Stage 128x32 bf16 tile (1 gload_lds / thread, 512 threads).
__device__ __forceinline__ void stage128(__bf16* dst, const __bf16* src, size_t ld, int tid) {
    const int w = tid >> 6, l = tid & 63;
    const int ri = l >> 2, o = l & 3;
    const int row = w * 16 + ri;
    gload_lds16(src + (size_t)row * ld + ((o ^ ((row >> 1) & 3)) << 3),
                dst + (size_t)(w * 16) * BKQ, l);
}

// -------- merged transpose+cvt: W1,W2 [H][F] -> [F][H]; W3 [F][H] -> [H][F] --
__global__ __launch_bounds__(256) void transpose_all_kernel(
    const float* __restrict__ W1, const float* __restrict__ W2,
    const float* __restrict__ W3, __bf16* __restrict__ wsb,
    int e_base, size_t slotElems)
{
    __shared__ float lds[64 * 68];
    const size_t MAT = (size_t)HID * FFN;
    const int t = threadIdx.x;
    const int m = blockIdx.y;
    const int e = e_base + blockIdx.z;

    const float* src;
    __bf16* dst;
    int C, csh;   // src is [R][C]; dst is [C][R]
    if (m == 0)      { src = W1 + (size_t)e * MAT; dst = wsb + (size_t)blockIdx.z * slotElems;           C = FFN; csh = 6; }
    else if (m == 1) { src = W2 + (size_t)e * MAT; dst = wsb + (size_t)blockIdx.z * slotElems + MAT;     C = FFN; csh = 6; }
    else             { src = W3 + (size_t)e * MAT; dst = wsb + (size_t)blockIdx.z * slotElems + 2 * MAT; C = HID; csh = 5; }
    const int R = (m == 2) ? FFN : HID;
    const int bx = blockIdx.x & ((1 << csh) - 1);
    const int by = blockIdx.x >> csh;
    const int c0 = bx * 64, r0 = by * 64;

    const int rr = t >> 4;
    const int cc = (t & 15) * 4;
#pragma unroll
    for (int p = 0; p < 4; ++p) {
        const int row = p * 16 + rr;
        f32x4 v = *(const f32x4*)(src + (size_t)(r0 + row) * C + c0 + cc);
        *(f32x4*)&lds[row * 68 + (cc ^ (((row >> 3) & 7) << 2))] = v;
    }
    __syncthreads();
    const int o  = t & 7;
    const int c2 = t >> 3;
#pragma unroll
    for (int q = 0; q < 2; ++q) {
        const int c = q * 32 + c2;
        bf16x8 b;
#pragma unroll
        for (int j = 0; j < 8; ++j) {
            b[j] = (__bf16)lds[(8 * o + j) * 68 + (c ^ (o << 2))];
        }
        *(bf16x8*)(dst + (size_t)(c0 + c) * R + r0 + 8 * o) = b;
    }
}

// -------- elementwise fp32 -> bf16 --------
__global__ __launch_bounds__(256) void cvt_kernel(const float* __restrict__ src,
                                                  __bf16* __restrict__ dst, size_t n) {
    const size_t i = ((size_t)blockIdx.x * 256 + threadIdx.x) * 8;
    if (i >= n) return;
    f32x4 v0 = *(const f32x4*)(src + i);
    f32x4 v1 = *(const f32x4*)(src + i + 4);
    bf16x8 b;
#pragma unroll
    for (int k = 0; k < 4; ++k) { b[k] = (__bf16)v0[k]; b[4 + k] = (__bf16)v1[k]; }
    *(bf16x8*)(dst + i) = b;
}

// ---------------- gateup: PERSISTENT dual GEMM 256x128, BK=32, 3-buf --------
#define BMU 256
#define BNU 128
#define GXU (FFN / BNU)              // 32
#define ASZ_GU (BMU * BKQ)           // 8192 elems
#define BSZ_GU (BNU * BKQ)           // 4096 elems
#define BUF_GU (ASZ_GU + 2 * BSZ_GU) // 16384 elems = 32 KiB

__global__ __launch_bounds__(512, 2) void gateup_kernel(
    const __bf16* __restrict__ Xb, const __bf16* __restrict__ wsb,
    const float* __restrict__ b1, const float* __restrict__ b2,
    int e_base, int nz, size_t slotElems)
{
    __shared__ __align__(16) __bf16 lds[3 * BUF_GU];   // 96 KiB
    const size_t MAT = (size_t)HID * FFN;
    const int tid = threadIdx.x;

    // bijective XCD swizzle (nwg=256); column decomposition: weights L2-pinned.
    int f = blockIdx.y * GXU + blockIdx.x;
    f = (f & 7) * ((GXU * (TOK / BMU)) >> 3) + (f >> 3);
    const int bx = f >> 3;                 // 0..31
    const int by = f & 7;                  // 0..7

    const int m0 = by * BMU;
    const int n0 = bx * BNU;

    const int w = tid >> 6, lane = tid & 63;
    const int wm = w >> 1, wn = w & 1;          // 4M x 2N waves, per-wave 64x64
    const int fr = lane & 15, fq = lane >> 4;

    f32x4 accG[4][4] = {};
    f32x4 accU[4][4] = {};

    const int NT = HID / BKQ;  // 64

    // z=0 pointers + prologue: stage tiles 0,1 (8 loads), wait tile0 (keep 4)
    const __bf16* gA  = Xb + (size_t)(e_base * TOK + m0) * HID;
    const __bf16* gB1 = wsb + (size_t)n0 * HID;
    const __bf16* gB2 = wsb + MAT + (size_t)n0 * HID;
#pragma unroll
    for (int t0 = 0; t0 < 2; ++t0) {
        __bf16* d = lds + t0 * BUF_GU;
        const size_t ko = (size_t)t0 * BKQ;
        stage256(d, gA + ko, HID, tid);
        stage128(d + ASZ_GU, gB1 + ko, HID, tid);
        stage128(d + ASZ_GU + BSZ_GU, gB2 + ko, HID, tid);
    }
    asm volatile("s_waitcnt vmcnt(4)" ::: "memory");
    __builtin_amdgcn_s_barrier();

    int cur = 0;
    for (int z = 0; z < nz; ++z) {
        const int e = e_base + z;
        const __bf16* base = wsb + (size_t)z * slotElems;

        for (int t = 0; t < NT; ++t) {
            const int nb = (cur == 0) ? 2 : cur - 1;   // (cur+2)%3
            __bf16* d = lds + nb * BUF_GU;
            const size_t ko2 = (size_t)(t + 2) * BKQ;
            const __bf16* bufA  = lds + cur * BUF_GU;
            const __bf16* bufB1 = bufA + ASZ_GU;
            const __bf16* bufB2 = bufB1 + BSZ_GU;

            // ---- phase A: gate ----
            bf16x8 a[4], bg[4];
#pragma unroll
            for (int i = 0; i < 4; ++i) a[i] = ldfrag32(bufA, wm * 64 + i * 16 + fr, fq);
#pragma unroll
            for (int j = 0; j < 4; ++j) bg[j] = ldfrag32(bufB1, wn * 64 + j * 16 + fr, fq);
            if (t + 2 < NT) stage256(d, gA + ko2, HID, tid);           // 2 loads
            asm volatile("" ::: "memory");
            __builtin_amdgcn_s_barrier();
            __builtin_amdgcn_s_setprio(1);
#pragma unroll
            for (int j = 0; j < 4; ++j)
#pragma unroll
                for (int i = 0; i < 4; ++i)
                    accG[i][j] = __builtin_amdgcn_mfma_f32_16x16x32_bf16(a[i], bg[j], accG[i][j], 0, 0, 0);
            __builtin_amdgcn_s_setprio(0);

            // ---- phase B: up ----
            bf16x8 bu[4];
#pragma unroll
            for (int j = 0; j < 4; ++j) bu[j] = ldfrag32(bufB2, wn * 64 + j * 16 + fr, fq);
            if (t + 2 < NT) {
                stage128(d + ASZ_GU, gB1 + ko2, HID, tid);             // 1 load
                stage128(d + ASZ_GU + BSZ_GU, gB2 + ko2, HID, tid);    // 1 load
            }
            if (t + 2 < NT)      asm volatile("s_waitcnt vmcnt(4)" ::: "memory");
            else if (t + 1 < NT) asm volatile("s_waitcnt vmcnt(0)" ::: "memory");
            if (t + 1 < NT) {
                asm volatile("" ::: "memory");
                __builtin_amdgcn_s_barrier();
            }
            __builtin_amdgcn_s_setprio(1);
#pragma unroll
            for (int j = 0; j < 4; ++j)
#pragma unroll
                for (int i = 0; i < 4; ++i)
                    accU[i][j] = __builtin_amdgcn_mfma_f32_16x16x32_bf16(a[i], bu[j], accU[i][j], 0, 0, 0);
            __builtin_amdgcn_s_setprio(0);

            cur = (cur == 2) ? 0 : cur + 1;
        }

        // ---- boundary: issue next-z prologue stages BEFORE epilogue stores ----
        if (z + 1 < nz) {
            const __bf16* base2 = wsb + (size_t)(z + 1) * slotElems;
            const __bf16* gA2  = Xb + (size_t)((e + 1) * TOK + m0) * HID;
            const __bf16* gB1n = base2 + (size_t)n0 * HID;
            const __bf16* gB2n = base2 + MAT + (size_t)n0 * HID;
            // tile k0 -> buf[cur], tile k1 -> buf[(cur+1)%3]  (8 loads)
            __bf16* d0 = lds + cur * BUF_GU;
            __bf16* d1 = lds + ((cur == 2) ? 0 : cur + 1) * BUF_GU;
            stage256(d0, gA2, HID, tid);
            stage128(d0 + ASZ_GU, gB1n, HID, tid);
            stage128(d0 + ASZ_GU + BSZ_GU, gB2n, HID, tid);
            stage256(d1, gA2 + BKQ, HID, tid);
            stage128(d1 + ASZ_GU, gB1n + BKQ, HID, tid);
            stage128(d1 + ASZ_GU + BSZ_GU, gB2n + BKQ, HID, tid);
            gA = gA2; gB1 = gB1n; gB2 = gB2n;
        }

        // ---- epilogue z: h = silu(gate+b1)*(up+b2) -> bf16 h [T][F] ----
        __bf16* gH = (__bf16*)(base + 3 * MAT) + (size_t)m0 * FFN + n0;
#pragma unroll
        for (int j = 0; j < 4; ++j) {
            const int col = wn * 64 + j * 16 + fr;
            const float bb1 = b1[(size_t)e * FFN + n0 + col];
            const float bb2 = b2[(size_t)e * FFN + n0 + col];
#pragma unroll
            for (int i = 0; i < 4; ++i) {
#pragma unroll
                for (int r = 0; r < 4; ++r) {
                    const int row = wm * 64 + i * 16 + fq * 4 + r;
                    const float g = accG[i][j][r] + bb1;
                    const float u = accU[i][j][r] + bb2;
                    const float s = g / (1.0f + __expf(-g));
                    gH[(size_t)row * FFN + col] = (__bf16)(s * u);
                }
            }
        }

        if (z + 1 < nz) {
            // reset accumulators for next expert
#pragma unroll
            for (int j = 0; j < 4; ++j)
#pragma unroll
                for (int i = 0; i < 4; ++i) {
                    accG[i][j] = f32x4{0.f, 0.f, 0.f, 0.f};
                    accU[i][j] = f32x4{0.f, 0.f, 0.f, 0.f};
                }
            // loads are oldest in FIFO; vmcnt(4) forces all 8 done (+most stores)
            asm volatile("s_waitcnt vmcnt(4)" ::: "memory");
            __builtin_amdgcn_s_barrier();
        }
    }
}

// ---------------- down: GEMM 256x256, BK=32, 3-buf pipeline (r18) -----------
#define BMD 256
#define BND 256
#define GXD (HID / BND)              // 8
#define ASZ_D (BMD * BKQ)            // 8192 elems
#define BUF_D (2 * ASZ_D)            // 16384 elems = 32 KiB

__global__ __launch_bounds__(512, 2) void down_kernel(
    const __bf16* __restrict__ wsb, const float* __restrict__ b3,
    const float* __restrict__ probs, float* __restrict__ out,
    int e_base, size_t slotElems)
{
    __shared__ __align__(16) __bf16 lds[3 * BUF_D];
    const size_t MAT = (size_t)HID * FFN;
    const int tid = threadIdx.x;

    int f = blockIdx.y * GXD + blockIdx.x;
    f = (f & 7) * ((GXD * (TOK / BMD)) >> 3) + (f >> 3);
    const int bx = f >> 3;                 // 0..7
    const int by = f & 7;                  // 0..7

    const int e  = e_base + blockIdx.z;
    const int m0 = by * BMD;
    const int n0 = bx * BND;

    const __bf16* base = wsb + (size_t)blockIdx.z * slotElems;
    const __bf16* gA   = base + 3 * MAT + (size_t)m0 * FFN;   // h [T][F]
    const __bf16* gB   = base + 2 * MAT + (size_t)n0 * FFN;   // W3T [H][F]

    const int w = tid >> 6, lane = tid & 63;
    const int wm = w >> 2, wn = w & 3;          // 2M x 4N waves, per-wave 128x64
    const int fr = lane & 15, fq = lane >> 4;

    f32x4 acc[8][4] = {};

    const int NT = FFN / BKQ;  // 128

#pragma unroll
    for (int t0 = 0; t0 < 2; ++t0) {
        __bf16* d = lds + t0 * BUF_D;
        const size_t ko = (size_t)t0 * BKQ;
        stage256(d, gA + ko, FFN, tid);
        stage256(d + ASZ_D, gB + ko, FFN, tid);
    }
    asm volatile("s_waitcnt vmcnt(4)" ::: "memory");
    __builtin_amdgcn_s_barrier();

    int cur = 0;
    for (int t = 0; t < NT; ++t) {
        const int nb = (cur == 0) ? 2 : cur - 1;   // (cur+2)%3
        __bf16* d = lds + nb * BUF_D;
        const size_t ko2 = (size_t)(t + 2) * BKQ;
        const __bf16* bufA = lds + cur * BUF_D;
        const __bf16* bufB = bufA + ASZ_D;

        // ---- phase A: m-half 0 ----
        bf16x8 a0[4], b[4];
#pragma unroll
        for (int i = 0; i < 4; ++i) a0[i] = ldfrag32(bufA, wm * 128 + i * 16 + fr, fq);
#pragma unroll
        for (int j = 0; j < 4; ++j) b[j] = ldfrag32(bufB, wn * 64 + j * 16 + fr, fq);
        if (t + 2 < NT) stage256(d, gA + ko2, FFN, tid);           // 2 loads
        asm volatile("" ::: "memory");
        __builtin_amdgcn_s_barrier();
        __builtin_amdgcn_s_setprio(1);
#pragma unroll
        for (int j = 0; j < 4; ++j)
#pragma unroll
            for (int i = 0; i < 4; ++i)
                acc[i][j] = __builtin_amdgcn_mfma_f32_16x16x32_bf16(a0[i], b[j], acc[i][j], 0, 0, 0);
        __builtin_amdgcn_s_setprio(0);

        // ---- phase B: m-half 1 ----
        bf16x8 a1[4];
#pragma unroll
        for (int i = 0; i < 4; ++i) a1[i] = ldfrag32(bufA, wm * 128 + (i + 4) * 16 + fr, fq);
        if (t + 2 < NT) stage256(d + ASZ_D, gB + ko2, FFN, tid);   // 2 loads
        if (t + 1 < NT) {
            if (t + 2 < NT) asm volatile("s_waitcnt vmcnt(4)" ::: "memory");
            else            asm volatile("s_waitcnt vmcnt(0)" ::: "memory");
        }
        asm volatile("" ::: "memory");
        __builtin_amdgcn_s_barrier();
        __builtin_amdgcn_s_setprio(1);
#pragma unroll
        for (int j = 0; j < 4; ++j)
#pragma unroll
            for (int i = 0; i < 4; ++i)
                acc[i + 4][j] = __builtin_amdgcn_mfma_f32_16x16x32_bf16(a1[i], b[j], acc[i + 4][j], 0, 0, 0);
        __builtin_amdgcn_s_setprio(0);

        cur = (cur == 2) ? 0 : cur + 1;
    }

    float* gO = out + (size_t)(e * TOK + m0) * HID + n0;
    float bb3[4];
#pragma unroll
    for (int j = 0; j < 4; ++j) bb3[j] = b3[(size_t)e * HID + n0 + wn * 64 + j * 16 + fr];
#pragma unroll
    for (int i = 0; i < 8; ++i) {
#pragma unroll
        for (int r = 0; r < 4; ++r) {
            const int row = wm * 128 + i * 16 + fq * 4 + r;
            const float pp = probs[(size_t)e * TOK + m0 + row];
            float* o = gO + (size_t)row * HID;
#pragma unroll
            for (int j = 0; j < 4; ++j) {
                o[wn * 64 + j * 16 + fr] = (acc[i][j][r] + bb3[j]) * pp;
            }
        }
    }
}

extern "C" void kernel_launch(void* const* d_in, const int* in_sizes, int n_in,
                              void* d_out, int out_size, void* d_ws, size_t ws_size,
                              hipStream_t stream) {
    const float* X     = (const float*)d_in[0];
    // d_in[1] tokens_per_expert (int64): equal split, unused
    const float* probs = (const float*)d_in[2];
    const float* W1    = (const float*)d_in[3];
    const float* b1    = (const float*)d_in[4];
    const float* W2    = (const float*)d_in[5];
    const float* b2    = (const float*)d_in[6];
    const float* W3    = (const float*)d_in[7];
    const float* b3    = (const float*)d_in[8];
    float* out = (float*)d_out;

    const size_t MAT = (size_t)HID * FFN;                  // 8,388,608 elems
    const size_t XBE = (size_t)EXPERTS * TOK * HID;        // 33,554,432 elems
    const size_t slotElems = 4 * MAT;                      // W1T,W2T,W3T,h

    int B = 4;  // measured best; B=8 regressed (r19), B=2 regressed (r7)
    while (B > 1 && ((size_t)B * slotElems + XBE) * sizeof(__bf16) > ws_size) B >>= 1;

    __bf16* wsb = (__bf16*)d_ws;
    __bf16* Xb  = wsb + (size_t)B * slotElems;

    // X -> bf16 once
    cvt_kernel<<<(int)(XBE / 8 / 256), 256, 0, stream>>>(X, Xb, XBE);

    for (int eb = 0; eb < EXPERTS; eb += B) {
        // merged: W1,W2 [H][F] -> [F][H]; W3 [F][H] -> [H][F]
        transpose_all_kernel<<<dim3(2048, 3, B), 256, 0, stream>>>(
            W1, W2, W3, wsb, eb, slotElems);

        // persistent: one generation of 256 blocks loops over B experts
        gateup_kernel<<<dim3(GXU, TOK / BMU, 1), 512, 0, stream>>>(
            Xb, wsb, b1, b2, eb, B, slotElems);
        down_kernel<<<dim3(GXD, TOK / BMD, B), 512, 0, stream>>>(
            wsb, b3, probs, out, eb, slotElems);
    }
}

// Round 23
// 998.563 us; speedup vs baseline: 1.0799x; 1.0799x over previous
//
#include <hip/hip_runtime.h>
#include <hip/hip_bf16.h>

// MoE experts MLP: E=8, T=2048, H=2048, F=4096, fp32 in/out.
// FINAL (= r18/r20 measured best, 999.1/999.5 us): B=4 expert batching.
// Pre-pass: X -> bf16 (Xb); ONE merged kernel transposes+converts W1,W2 ->
// W1T,W2T [F][H] bf16 and W3 -> W3T [H][F] bf16 (blockIdx.y = matrix).
// gateup: h = silu(x@W1+b1)*(x@W2+b2) -> bf16 h [T][F] (ws), dual-GEMM 256x128.
// down:   out = (h@W3 + b3) * probs, GEMM 256x256.
// GEMM structure: BK=32, 512 thr/8 waves, 3-buffer LDS rotation, distance-2
// prefetch, counted vmcnt(4) (0 only at tail), 2-phase K-step,
// global_load_lds(16B) pre-swizzled source (conflict-free XOR swizzle),
// setprio around MFMA, XCD COLUMN grouping (FETCH 541->197 MB/dispatch),
// launch_bounds(512,2) (VGPR floor ~140; (512,4) spills - r12).
// Falsified levers (22 rounds): 4-phase, BK=64 dbuf, small tiles (2x FETCH),
// read-ahead regs, 2-buf multi-block (x2), 32x32x16 (bank conflicts),
// B-via-regs (L2 scatter), B=2/B=8 batching, single-GEMM gateup (identical),
// persistent gateup (VGPR cap + pinning dilution).

#define EXPERTS 8
#define TOK 2048
#define HID 2048
#define FFN 4096

#define BKQ 32

typedef float f32x4 __attribute__((ext_vector_type(4)));
typedef __bf16 bf16x8 __attribute__((ext_vector_type(8)));

#if defined(__has_builtin)
#if __has_builtin(__builtin_amdgcn_global_load_lds)
#define HAVE_GLL 1
#endif
#endif

__device__ __forceinline__ void gload_lds16(const __bf16* g, __bf16* l, int lane) {
#ifdef HAVE_GLL
    __builtin_amdgcn_global_load_lds((const __attribute__((address_space(1))) void*)g,
                                     (__attribute__((address_space(3))) void*)l,
                                     16, 0, 0);
#else
    bf16x8 v = *(const bf16x8*)g;
    *(bf16x8*)(l + lane * 8) = v;
#endif
}

// BK=32 rows are 4 octets; swizzle o ^ ((row>>1)&3): conflict-free (measured 0).
__device__ __forceinline__ bf16x8 ldfrag32(const __bf16* s, int row, int fq) {
    return *(const bf16x8*)(s + row * BKQ + ((fq ^ ((row >> 1) & 3)) << 3));
}

// Stage 256x32 bf16 tile (2 gload_lds / thread, 512 threads).
__device__ __forceinline__ void stage256(__bf16* dst, const __bf16* src, size_t ld, int tid) {
    const int w = tid >> 6, l = tid & 63;
    const int ri = l >> 2, o = l & 3;
#pragma unroll
    for (int q = 0; q < 2; ++q) {
        const int row = q * 128 + w * 16 + ri;
        gload_lds16(src + (size_t)row * ld + ((o ^ ((row >> 1) & 3)) << 3),
                    dst + (size_t)(q * 128 + w * 16) * BKQ, l);
    }
}

// Stage 128x32 bf16 tile (1 gload_lds / thread, 512 threads).
__device__ __forceinline__ void stage128(__bf16* dst, const __bf16* src, size_t ld, int tid) {
    const int w = tid >> 6, l = tid & 63;
    const int ri = l >> 2, o = l & 3;
    const int row = w * 16 + ri;
    gload_lds16(src + (size_t)row * ld + ((o ^ ((row >> 1) & 3)) << 3),
                dst + (size_t)(w * 16) * BKQ, l);
}

// -------- merged transpose+cvt: W1,W2 [H][F] -> [F][H]; W3 [F][H] -> [H][F] --
// blockIdx.y: 0=W1, 1=W2, 2=W3. blockIdx.z = expert within batch.
__global__ __launch_bounds__(256) void transpose_all_kernel(
    const float* __restrict__ W1, const float* __restrict__ W2,
    const float* __restrict__ W3, __bf16* __restrict__ wsb,
    int e_base, size_t slotElems)
{
    __shared__ float lds[64 * 68];
    const size_t MAT = (size_t)HID * FFN;
    const int t = threadIdx.x;
    const int m = blockIdx.y;
    const int e = e_base + blockIdx.z;

    const float* src;
    __bf16* dst;
    int C, csh;   // src is [R][C]; dst is [C][R]
    if (m == 0)      { src = W1 + (size_t)e * MAT; dst = wsb + (size_t)blockIdx.z * slotElems;           C = FFN; csh = 6; }
    else if (m == 1) { src = W2 + (size_t)e * MAT; dst = wsb + (size_t)blockIdx.z * slotElems + MAT;     C = FFN; csh = 6; }
    else             { src = W3 + (size_t)e * MAT; dst = wsb + (size_t)blockIdx.z * slotElems + 2 * MAT; C = HID; csh = 5; }
    const int R = (m == 2) ? FFN : HID;
    const int bx = blockIdx.x & ((1 << csh) - 1);
    const int by = blockIdx.x >> csh;
    const int c0 = bx * 64, r0 = by * 64;

    const int rr = t >> 4;
    const int cc = (t & 15) * 4;
#pragma unroll
    for (int p = 0; p < 4; ++p) {
        const int row = p * 16 + rr;
        f32x4 v = *(const f32x4*)(src + (size_t)(r0 + row) * C + c0 + cc);
        *(f32x4*)&lds[row * 68 + (cc ^ (((row >> 3) & 7) << 2))] = v;
    }
    __syncthreads();
    const int o  = t & 7;
    const int c2 = t >> 3;
#pragma unroll
    for (int q = 0; q < 2; ++q) {
        const int c = q * 32 + c2;
        bf16x8 b;
#pragma unroll
        for (int j = 0; j < 8; ++j) {
            b[j] = (__bf16)lds[(8 * o + j) * 68 + (c ^ (o << 2))];
        }
        *(bf16x8*)(dst + (size_t)(c0 + c) * R + r0 + 8 * o) = b;
    }
}

// -------- elementwise fp32 -> bf16 --------
__global__ __launch_bounds__(256) void cvt_kernel(const float* __restrict__ src,
                                                  __bf16* __restrict__ dst, size_t n) {
    const size_t i = ((size_t)blockIdx.x * 256 + threadIdx.x) * 8;
    if (i >= n) return;
    f32x4 v0 = *(const f32x4*)(src + i);
    f32x4 v1 = *(const f32x4*)(src + i + 4);
    bf16x8 b;
#pragma unroll
    for (int k = 0; k < 4; ++k) { b[k] = (__bf16)v0[k]; b[4 + k] = (__bf16)v1[k]; }
    *(bf16x8*)(dst + i) = b;
}

// ---------------- gateup: dual GEMM 256x128, BK=32, 3-buf pipeline ----------
#define BMU 256
#define BNU 128
#define GXU (FFN / BNU)              // 32
#define ASZ_GU (BMU * BKQ)           // 8192 elems
#define BSZ_GU (BNU * BKQ)           // 4096 elems
#define BUF_GU (ASZ_GU + 2 * BSZ_GU) // 16384 elems = 32 KiB

__global__ __launch_bounds__(512, 2) void gateup_kernel(
    const __bf16* __restrict__ Xb, const __bf16* __restrict__ wsb,
    const float* __restrict__ b1, const float* __restrict__ b2,
    int e_base, size_t slotElems)
{
    __shared__ __align__(16) __bf16 lds[3 * BUF_GU];   // 96 KiB
    const size_t MAT = (size_t)HID * FFN;
    const int tid = threadIdx.x;

    // bijective XCD swizzle (nwg=256); column decomposition: weights L2-pinned.
    int f = blockIdx.y * GXU + blockIdx.x;
    f = (f & 7) * ((GXU * (TOK / BMU)) >> 3) + (f >> 3);
    const int bx = f >> 3;                 // 0..31
    const int by = f & 7;                  // 0..7

    const int e  = e_base + blockIdx.z;
    const int m0 = by * BMU;
    const int n0 = bx * BNU;

    const __bf16* base = wsb + (size_t)blockIdx.z * slotElems;
    const __bf16* gA   = Xb + (size_t)(e * TOK + m0) * HID;
    const __bf16* gB1  = base + (size_t)n0 * HID;
    const __bf16* gB2  = base + MAT + (size_t)n0 * HID;

    const int w = tid >> 6, lane = tid & 63;
    const int wm = w >> 1, wn = w & 1;          // 4M x 2N waves, per-wave 64x64
    const int fr = lane & 15, fq = lane >> 4;

    f32x4 accG[4][4] = {};
    f32x4 accU[4][4] = {};

    const int NT = HID / BKQ;  // 64

    // prologue: stage tiles 0 -> buf0, 1 -> buf1 (8 loads), wait tile0 (keep 4)
#pragma unroll
    for (int t0 = 0; t0 < 2; ++t0) {
        __bf16* d = lds + t0 * BUF_GU;
        const size_t ko = (size_t)t0 * BKQ;
        stage256(d, gA + ko, HID, tid);
        stage128(d + ASZ_GU, gB1 + ko, HID, tid);
        stage128(d + ASZ_GU + BSZ_GU, gB2 + ko, HID, tid);
    }
    asm volatile("s_waitcnt vmcnt(4)" ::: "memory");
    __builtin_amdgcn_s_barrier();

    int cur = 0;
    for (int t = 0; t < NT; ++t) {
        const int nb = (cur == 0) ? 2 : cur - 1;   // (cur+2)%3
        __bf16* d = lds + nb * BUF_GU;
        const size_t ko2 = (size_t)(t + 2) * BKQ;
        const __bf16* bufA  = lds + cur * BUF_GU;
        const __bf16* bufB1 = bufA + ASZ_GU;
        const __bf16* bufB2 = bufB1 + BSZ_GU;

        // ---- phase A: gate ----
        bf16x8 a[4], bg[4];
#pragma unroll
        for (int i = 0; i < 4; ++i) a[i] = ldfrag32(bufA, wm * 64 + i * 16 + fr, fq);
#pragma unroll
        for (int j = 0; j < 4; ++j) bg[j] = ldfrag32(bufB1, wn * 64 + j * 16 + fr, fq);
        if (t + 2 < NT) stage256(d, gA + ko2, HID, tid);           // 2 loads
        asm volatile("" ::: "memory");
        __builtin_amdgcn_s_barrier();
        __builtin_amdgcn_s_setprio(1);
#pragma unroll
        for (int j = 0; j < 4; ++j)
#pragma unroll
            for (int i = 0; i < 4; ++i)
                accG[i][j] = __builtin_amdgcn_mfma_f32_16x16x32_bf16(a[i], bg[j], accG[i][j], 0, 0, 0);
        __builtin_amdgcn_s_setprio(0);

        // ---- phase B: up ----
        bf16x8 bu[4];
#pragma unroll
        for (int j = 0; j < 4; ++j) bu[j] = ldfrag32(bufB2, wn * 64 + j * 16 + fr, fq);
        if (t + 2 < NT) {
            stage128(d + ASZ_GU, gB1 + ko2, HID, tid);             // 1 load
            stage128(d + ASZ_GU + BSZ_GU, gB2 + ko2, HID, tid);    // 1 load
        }
        if (t + 1 < NT) {
            if (t + 2 < NT) asm volatile("s_waitcnt vmcnt(4)" ::: "memory");
            else            asm volatile("s_waitcnt vmcnt(0)" ::: "memory");
        }
        asm volatile("" ::: "memory");
        __builtin_amdgcn_s_barrier();
        __builtin_amdgcn_s_setprio(1);
#pragma unroll
        for (int j = 0; j < 4; ++j)
#pragma unroll
            for (int i = 0; i < 4; ++i)
                accU[i][j] = __builtin_amdgcn_mfma_f32_16x16x32_bf16(a[i], bu[j], accU[i][j], 0, 0, 0);
        __builtin_amdgcn_s_setprio(0);

        cur = (cur == 2) ? 0 : cur + 1;
    }

    // epilogue: h = silu(gate+b1)*(up+b2) -> bf16 h [T][F] in ws slot
    __bf16* gH = (__bf16*)(base + 3 * MAT) + (size_t)m0 * FFN + n0;
#pragma unroll
    for (int j = 0; j < 4; ++j) {
        const int col = wn * 64 + j * 16 + fr;
        const float bb1 = b1[(size_t)e * FFN + n0 + col];
        const float bb2 = b2[(size_t)e * FFN + n0 + col];
#pragma unroll
        for (int i = 0; i < 4; ++i) {
#pragma unroll
            for (int r = 0; r < 4; ++r) {
                const int row = wm * 64 + i * 16 + fq * 4 + r;
                const float g = accG[i][j][r] + bb1;
                const float u = accU[i][j][r] + bb2;
                const float s = g / (1.0f + __expf(-g));
                gH[(size_t)row * FFN + col] = (__bf16)(s * u);
            }
        }
    }
}

// ---------------- down: GEMM 256x256, BK=32, 3-buf pipeline ----------------
#define BMD 256
#define BND 256
#define GXD (HID / BND)              // 8
#define ASZ_D (BMD * BKQ)            // 8192 elems
#define BUF_D (2 * ASZ_D)            // 16384 elems = 32 KiB

__global__ __launch_bounds__(512, 2) void down_kernel(
    const __bf16* __restrict__ wsb, const float* __restrict__ b3,
    const float* __restrict__ probs, float* __restrict__ out,
    int e_base, size_t slotElems)
{
    __shared__ __align__(16) __bf16 lds[3 * BUF_D];
    const size_t MAT = (size_t)HID * FFN;
    const int tid = threadIdx.x;

    // bijective XCD swizzle (nwg=64); column decomposition: W3T L2-pinned.
    int f = blockIdx.y * GXD + blockIdx.x;
    f = (f & 7) * ((GXD * (TOK / BMD)) >> 3) + (f >> 3);
    const int bx = f >> 3;                 // 0..7
    const int by = f & 7;                  // 0..7

    const int e  = e_base + blockIdx.z;
    const int m0 = by * BMD;
    const int n0 = bx * BND;

    const __bf16* base = wsb + (size_t)blockIdx.z * slotElems;
    const __bf16* gA   = base + 3 * MAT + (size_t)m0 * FFN;   // h [T][F]
    const __bf16* gB   = base + 2 * MAT + (size_t)n0 * FFN;   // W3T [H][F]

    const int w = tid >> 6, lane = tid & 63;
    const int wm = w >> 2, wn = w & 3;          // 2M x 4N waves, per-wave 128x64
    const int fr = lane & 15, fq = lane >> 4;

    f32x4 acc[8][4] = {};

    const int NT = FFN / BKQ;  // 128

#pragma unroll
    for (int t0 = 0; t0 < 2; ++t0) {
        __bf16* d = lds + t0 * BUF_D;
        const size_t ko = (size_t)t0 * BKQ;
        stage256(d, gA + ko, FFN, tid);
        stage256(d + ASZ_D, gB + ko, FFN, tid);
    }
    asm volatile("s_waitcnt vmcnt(4)" ::: "memory");
    __builtin_amdgcn_s_barrier();

    int cur = 0;
    for (int t = 0; t < NT; ++t) {
        const int nb = (cur == 0) ? 2 : cur - 1;   // (cur+2)%3
        __bf16* d = lds + nb * BUF_D;
        const size_t ko2 = (size_t)(t + 2) * BKQ;
        const __bf16* bufA = lds + cur * BUF_D;
        const __bf16* bufB = bufA + ASZ_D;

        // ---- phase A: m-half 0 ----
        bf16x8 a0[4], b[4];
#pragma unroll
        for (int i = 0; i < 4; ++i) a0[i] = ldfrag32(bufA, wm * 128 + i * 16 + fr, fq);
#pragma unroll
        for (int j = 0; j < 4; ++j) b[j] = ldfrag32(bufB, wn * 64 + j * 16 + fr, fq);
        if (t + 2 < NT) stage256(d, gA + ko2, FFN, tid);           // 2 loads
        asm volatile("" ::: "memory");
        __builtin_amdgcn_s_barrier();
        __builtin_amdgcn_s_setprio(1);
#pragma unroll
        for (int j = 0; j < 4; ++j)
#pragma unroll
            for (int i = 0; i < 4; ++i)
                acc[i][j] = __builtin_amdgcn_mfma_f32_16x16x32_bf16(a0[i], b[j], acc[i][j], 0, 0, 0);
        __builtin_amdgcn_s_setprio(0);

        // ---- phase B: m-half 1 ----
        bf16x8 a1[4];
#pragma unroll
        for (int i = 0; i < 4; ++i) a1[i] = ldfrag32(bufA, wm * 128 + (i + 4) * 16 + fr, fq);
        if (t + 2 < NT) stage256(d + ASZ_D, gB + ko2, FFN, tid);   // 2 loads
        if (t + 1 < NT) {
            if (t + 2 < NT) asm volatile("s_waitcnt vmcnt(4)" ::: "memory");
            else            asm volatile("s_waitcnt vmcnt(0)" ::: "memory");
        }
        asm volatile("" ::: "memory");
        __builtin_amdgcn_s_barrier();
        __builtin_amdgcn_s_setprio(1);
#pragma unroll
        for (int j = 0; j < 4; ++j)
#pragma unroll
            for (int i = 0; i < 4; ++i)
                acc[i + 4][j] = __builtin_amdgcn_mfma_f32_16x16x32_bf16(a1[i], b[j], acc[i + 4][j], 0, 0, 0);
        __builtin_amdgcn_s_setprio(0);

        cur = (cur == 2) ? 0 : cur + 1;
    }

    float* gO = out + (size_t)(e * TOK + m0) * HID + n0;
    float bb3[4];
#pragma unroll
    for (int j = 0; j < 4; ++j) bb3[j] = b3[(size_t)e * HID + n0 + wn * 64 + j * 16 + fr];
#pragma unroll
    for (int i = 0; i < 8; ++i) {
#pragma unroll
        for (int r = 0; r < 4; ++r) {
            const int row = wm * 128 + i * 16 + fq * 4 + r;
            const float pp = probs[(size_t)e * TOK + m0 + row];
            float* o = gO + (size_t)row * HID;
#pragma unroll
            for (int j = 0; j < 4; ++j) {
                o[wn * 64 + j * 16 + fr] = (acc[i][j][r] + bb3[j]) * pp;
            }
        }
    }
}

extern "C" void kernel_launch(void* const* d_in, const int* in_sizes, int n_in,
                              void* d_out, int out_size, void* d_ws, size_t ws_size,
                              hipStream_t stream) {
    const float* X     = (const float*)d_in[0];
    // d_in[1] tokens_per_expert (int64): equal split, unused
    const float* probs = (const float*)d_in[2];
    const float* W1    = (const float*)d_in[3];
    const float* b1    = (const float*)d_in[4];
    const float* W2    = (const float*)d_in[5];
    const float* b2    = (const float*)d_in[6];
    const float* W3    = (const float*)d_in[7];
    const float* b3    = (const float*)d_in[8];
    float* out = (float*)d_out;

    const size_t MAT = (size_t)HID * FFN;                  // 8,388,608 elems
    const size_t XBE = (size_t)EXPERTS * TOK * HID;        // 33,554,432 elems
    const size_t slotElems = 4 * MAT;                      // W1T,W2T,W3T,h

    int B = 4;  // measured best; B=8 regressed (r19), B=2 regressed (r7)
    while (B > 1 && ((size_t)B * slotElems + XBE) * sizeof(__bf16) > ws_size) B >>= 1;

    __bf16* wsb = (__bf16*)d_ws;
    __bf16* Xb  = wsb + (size_t)B * slotElems;

    // X -> bf16 once
    cvt_kernel<<<(int)(XBE / 8 / 256), 256, 0, stream>>>(X, Xb, XBE);

    for (int eb = 0; eb < EXPERTS; eb += B) {
        // one merged launch: W1,W2 [H][F] -> [F][H]; W3 [F][H] -> [H][F]
        transpose_all_kernel<<<dim3(2048, 3, B), 256, 0, stream>>>(
            W1, W2, W3, wsb, eb, slotElems);

        gateup_kernel<<<dim3(GXU, TOK / BMU, B), 512, 0, stream>>>(
            Xb, wsb, b1, b2, eb, slotElems);
        down_kernel<<<dim3(GXD, TOK / BMD, B), 512, 0, stream>>>(
            wsb, b3, probs, out, eb, slotElems);
    }
}

// Round 24
// 978.044 us; speedup vs baseline: 1.1025x; 1.0210x over previous
//
#include <hip/hip_runtime.h>
#include <hip/hip_bf16.h>

// MoE experts MLP: E=8, T=2048, H=2048, F=4096, fp32 in/out.
// Base = r18 measured best (999 us, reproduced 3x). r24 change: DOWN kernel
// ported to the m201-style 8-PHASE counted-vmcnt schedule (BK=64, 2 K-tiles
// per iter, 2 LDS dbufs of 64 KiB, per-phase {quadrant ds-reads | stage 1
// half-tile | barrier | lgkmcnt(0) | setprio 16xMFMA | barrier}, vmcnt(4)
// only at phases 4 and 8, 0 only at tail). Quadrant order Q00,Q01,Q10,Q11
// per K-tile; stage order B0,B1,A0,A1 issued 4-7 phases before consumption;
// ledger hand-verified (see per-phase comments). Gateup/transposes/cvt are
// byte-identical to r18 (bank protected; A/B isolates the 8-phase effect).

#define EXPERTS 8
#define TOK 2048
#define HID 2048
#define FFN 4096

#define BKQ 32

typedef float f32x4 __attribute__((ext_vector_type(4)));
typedef __bf16 bf16x8 __attribute__((ext_vector_type(8)));

#if defined(__has_builtin)
#if __has_builtin(__builtin_amdgcn_global_load_lds)
#define HAVE_GLL 1
#endif
#endif

__device__ __forceinline__ void gload_lds16(const __bf16* g, __bf16* l, int lane) {
#ifdef HAVE_GLL
    __builtin_amdgcn_global_load_lds((const __attribute__((address_space(1))) void*)g,
                                     (__attribute__((address_space(3))) void*)l,
                                     16, 0, 0);
#else
    bf16x8 v = *(const bf16x8*)g;
    *(bf16x8*)(l + lane * 8) = v;
#endif
}

// BK=32 rows are 4 octets; swizzle o ^ ((row>>1)&3): conflict-free (measured 0).
__device__ __forceinline__ bf16x8 ldfrag32(const __bf16* s, int row, int fq) {
    return *(const bf16x8*)(s + row * BKQ + ((fq ^ ((row >> 1) & 3)) << 3));
}

// Stage 256x32 bf16 tile (2 gload_lds / thread, 512 threads), BK=32 layout.
__device__ __forceinline__ void stage256(__bf16* dst, const __bf16* src, size_t ld, int tid) {
    const int w = tid >> 6, l = tid & 63;
    const int ri = l >> 2, o = l & 3;
#pragma unroll
    for (int q = 0; q < 2; ++q) {
        const int row = q * 128 + w * 16 + ri;
        gload_lds16(src + (size_t)row * ld + ((o ^ ((row >> 1) & 3)) << 3),
                    dst + (size_t)(q * 128 + w * 16) * BKQ, l);
    }
}

// Stage 128x32 bf16 tile (1 gload_lds / thread, 512 threads), BK=32 layout.
__device__ __forceinline__ void stage128(__bf16* dst, const __bf16* src, size_t ld, int tid) {
    const int w = tid >> 6, l = tid & 63;
    const int ri = l >> 2, o = l & 3;
    const int row = w * 16 + ri;
    gload_lds16(src + (size_t)row * ld + ((o ^ ((row >> 1) & 3)) << 3),
                dst + (size_t)(w * 16) * BKQ, l);
}

// ---- BK=64 primitives (verified r9: correct + 0 bank conflicts) ----
#define BKD 64
__device__ __forceinline__ bf16x8 ldfrag64(const __bf16* s, int row, int oct) {
    return *(const bf16x8*)(s + row * BKD + ((oct ^ (row & 7)) << 3));
}

// Stage 128x64 half-tile (2 gload_lds / thread, 512 threads), BK=64 layout.
__device__ __forceinline__ void stageH64(__bf16* dst, const __bf16* src, size_t ld, int tid) {
    const int w = tid >> 6, l = tid & 63;
    const int ri = l >> 3, o = l & 7;
#pragma unroll
    for (int q = 0; q < 2; ++q) {
        const int row = q * 64 + w * 8 + ri;
        gload_lds16(src + (size_t)row * ld + ((o ^ ri) << 3),
                    dst + (size_t)(q * 64 + w * 8) * BKD, l);
    }
}

// -------- merged transpose+cvt: W1,W2 [H][F] -> [F][H]; W3 [F][H] -> [H][F] --
__global__ __launch_bounds__(256) void transpose_all_kernel(
    const float* __restrict__ W1, const float* __restrict__ W2,
    const float* __restrict__ W3, __bf16* __restrict__ wsb,
    int e_base, size_t slotElems)
{
    __shared__ float lds[64 * 68];
    const size_t MAT = (size_t)HID * FFN;
    const int t = threadIdx.x;
    const int m = blockIdx.y;
    const int e = e_base + blockIdx.z;

    const float* src;
    __bf16* dst;
    int C, csh;   // src is [R][C]; dst is [C][R]
    if (m == 0)      { src = W1 + (size_t)e * MAT; dst = wsb + (size_t)blockIdx.z * slotElems;           C = FFN; csh = 6; }
    else if (m == 1) { src = W2 + (size_t)e * MAT; dst = wsb + (size_t)blockIdx.z * slotElems + MAT;     C = FFN; csh = 6; }
    else             { src = W3 + (size_t)e * MAT; dst = wsb + (size_t)blockIdx.z * slotElems + 2 * MAT; C = HID; csh = 5; }
    const int R = (m == 2) ? FFN : HID;
    const int bx = blockIdx.x & ((1 << csh) - 1);
    const int by = blockIdx.x >> csh;
    const int c0 = bx * 64, r0 = by * 64;

    const int rr = t >> 4;
    const int cc = (t & 15) * 4;
#pragma unroll
    for (int p = 0; p < 4; ++p) {
        const int row = p * 16 + rr;
        f32x4 v = *(const f32x4*)(src + (size_t)(r0 + row) * C + c0 + cc);
        *(f32x4*)&lds[row * 68 + (cc ^ (((row >> 3) & 7) << 2))] = v;
    }
    __syncthreads();
    const int o  = t & 7;
    const int c2 = t >> 3;
#pragma unroll
    for (int q = 0; q < 2; ++q) {
        const int c = q * 32 + c2;
        bf16x8 b;
#pragma unroll
        for (int j = 0; j < 8; ++j) {
            b[j] = (__bf16)lds[(8 * o + j) * 68 + (c ^ (o << 2))];
        }
        *(bf16x8*)(dst + (size_t)(c0 + c) * R + r0 + 8 * o) = b;
    }
}

// -------- elementwise fp32 -> bf16 --------
__global__ __launch_bounds__(256) void cvt_kernel(const float* __restrict__ src,
                                                  __bf16* __restrict__ dst, size_t n) {
    const size_t i = ((size_t)blockIdx.x * 256 + threadIdx.x) * 8;
    if (i >= n) return;
    f32x4 v0 = *(const f32x4*)(src + i);
    f32x4 v1 = *(const f32x4*)(src + i + 4);
    bf16x8 b;
#pragma unroll
    for (int k = 0; k < 4; ++k) { b[k] = (__bf16)v0[k]; b[4 + k] = (__bf16)v1[k]; }
    *(bf16x8*)(dst + i) = b;
}

// ---------------- gateup: dual GEMM 256x128, BK=32, 3-buf (r18 exact) -------
#define BMU 256
#define BNU 128
#define GXU (FFN / BNU)              // 32
#define ASZ_GU (BMU * BKQ)           // 8192 elems
#define BSZ_GU (BNU * BKQ)           // 4096 elems
#define BUF_GU (ASZ_GU + 2 * BSZ_GU) // 16384 elems = 32 KiB

__global__ __launch_bounds__(512, 2) void gateup_kernel(
    const __bf16* __restrict__ Xb, const __bf16* __restrict__ wsb,
    const float* __restrict__ b1, const float* __restrict__ b2,
    int e_base, size_t slotElems)
{
    __shared__ __align__(16) __bf16 lds[3 * BUF_GU];   // 96 KiB
    const size_t MAT = (size_t)HID * FFN;
    const int tid = threadIdx.x;

    int f = blockIdx.y * GXU + blockIdx.x;
    f = (f & 7) * ((GXU * (TOK / BMU)) >> 3) + (f >> 3);
    const int bx = f >> 3;                 // 0..31
    const int by = f & 7;                  // 0..7

    const int e  = e_base + blockIdx.z;
    const int m0 = by * BMU;
    const int n0 = bx * BNU;

    const __bf16* base = wsb + (size_t)blockIdx.z * slotElems;
    const __bf16* gA   = Xb + (size_t)(e * TOK + m0) * HID;
    const __bf16* gB1  = base + (size_t)n0 * HID;
    const __bf16* gB2  = base + MAT + (size_t)n0 * HID;

    const int w = tid >> 6, lane = tid & 63;
    const int wm = w >> 1, wn = w & 1;
    const int fr = lane & 15, fq = lane >> 4;

    f32x4 accG[4][4] = {};
    f32x4 accU[4][4] = {};

    const int NT = HID / BKQ;  // 64

#pragma unroll
    for (int t0 = 0; t0 < 2; ++t0) {
        __bf16* d = lds + t0 * BUF_GU;
        const size_t ko = (size_t)t0 * BKQ;
        stage256(d, gA + ko, HID, tid);
        stage128(d + ASZ_GU, gB1 + ko, HID, tid);
        stage128(d + ASZ_GU + BSZ_GU, gB2 + ko, HID, tid);
    }
    asm volatile("s_waitcnt vmcnt(4)" ::: "memory");
    __builtin_amdgcn_s_barrier();

    int cur = 0;
    for (int t = 0; t < NT; ++t) {
        const int nb = (cur == 0) ? 2 : cur - 1;   // (cur+2)%3
        __bf16* d = lds + nb * BUF_GU;
        const size_t ko2 = (size_t)(t + 2) * BKQ;
        const __bf16* bufA  = lds + cur * BUF_GU;
        const __bf16* bufB1 = bufA + ASZ_GU;
        const __bf16* bufB2 = bufB1 + BSZ_GU;

        bf16x8 a[4], bg[4];
#pragma unroll
        for (int i = 0; i < 4; ++i) a[i] = ldfrag32(bufA, wm * 64 + i * 16 + fr, fq);
#pragma unroll
        for (int j = 0; j < 4; ++j) bg[j] = ldfrag32(bufB1, wn * 64 + j * 16 + fr, fq);
        if (t + 2 < NT) stage256(d, gA + ko2, HID, tid);
        asm volatile("" ::: "memory");
        __builtin_amdgcn_s_barrier();
        __builtin_amdgcn_s_setprio(1);
#pragma unroll
        for (int j = 0; j < 4; ++j)
#pragma unroll
            for (int i = 0; i < 4; ++i)
                accG[i][j] = __builtin_amdgcn_mfma_f32_16x16x32_bf16(a[i], bg[j], accG[i][j], 0, 0, 0);
        __builtin_amdgcn_s_setprio(0);

        bf16x8 bu[4];
#pragma unroll
        for (int j = 0; j < 4; ++j) bu[j] = ldfrag32(bufB2, wn * 64 + j * 16 + fr, fq);
        if (t + 2 < NT) {
            stage128(d + ASZ_GU, gB1 + ko2, HID, tid);
            stage128(d + ASZ_GU + BSZ_GU, gB2 + ko2, HID, tid);
        }
        if (t + 1 < NT) {
            if (t + 2 < NT) asm volatile("s_waitcnt vmcnt(4)" ::: "memory");
            else            asm volatile("s_waitcnt vmcnt(0)" ::: "memory");
        }
        asm volatile("" ::: "memory");
        __builtin_amdgcn_s_barrier();
        __builtin_amdgcn_s_setprio(1);
#pragma unroll
        for (int j = 0; j < 4; ++j)
#pragma unroll
            for (int i = 0; i < 4; ++i)
                accU[i][j] = __builtin_amdgcn_mfma_f32_16x16x32_bf16(a[i], bu[j], accU[i][j], 0, 0, 0);
        __builtin_amdgcn_s_setprio(0);

        cur = (cur == 2) ? 0 : cur + 1;
    }

    __bf16* gH = (__bf16*)(base + 3 * MAT) + (size_t)m0 * FFN + n0;
#pragma unroll
    for (int j = 0; j < 4; ++j) {
        const int col = wn * 64 + j * 16 + fr;
        const float bb1 = b1[(size_t)e * FFN + n0 + col];
        const float bb2 = b2[(size_t)e * FFN + n0 + col];
#pragma unroll
        for (int i = 0; i < 4; ++i) {
#pragma unroll
            for (int r = 0; r < 4; ++r) {
                const int row = wm * 64 + i * 16 + fq * 4 + r;
                const float g = accG[i][j][r] + bb1;
                const float u = accU[i][j][r] + bb2;
                const float s = g / (1.0f + __expf(-g));
                gH[(size_t)row * FFN + col] = (__bf16)(s * u);
            }
        }
    }
}

// ---------------- down: GEMM 256x256, BK=64, 8-PHASE counted pipeline -------
#define BMD 256
#define BND 256
#define GXD (HID / BND)              // 8
#define AHALF (128 * BKD)            // 8192 elems (128x64 half-tile)
#define ATILE (2 * AHALF)            // 16384 elems (256x64)
#define DBUFD (2 * ATILE)            // A + B per dbuf = 32768 elems (64 KiB)

__global__ __launch_bounds__(512, 2) void down_kernel(
    const __bf16* __restrict__ wsb, const float* __restrict__ b3,
    const float* __restrict__ probs, float* __restrict__ out,
    int e_base, size_t slotElems)
{
    __shared__ __align__(16) __bf16 lds[2 * DBUFD];   // 128 KiB
    const size_t MAT = (size_t)HID * FFN;
    const int tid = threadIdx.x;

    // bijective XCD swizzle (nwg=64); column decomposition: W3T L2-pinned.
    int f = blockIdx.y * GXD + blockIdx.x;
    f = (f & 7) * ((GXD * (TOK / BMD)) >> 3) + (f >> 3);
    const int bx = f >> 3;                 // 0..7
    const int by = f & 7;                  // 0..7

    const int e  = e_base + blockIdx.z;
    const int m0 = by * BMD;
    const int n0 = bx * BND;

    const __bf16* base = wsb + (size_t)blockIdx.z * slotElems;
    const __bf16* gA   = base + 3 * MAT + (size_t)m0 * FFN;   // h [T][F]
    const __bf16* gB   = base + 2 * MAT + (size_t)n0 * FFN;   // W3T [H][F]

    const int w = tid >> 6, lane = tid & 63;
    const int wm = w >> 2, wn = w & 3;          // 2M x 4N waves, per-wave 128x64
    const int fr = lane & 15, fq = lane >> 4;

    __bf16* AE = lds;                 // even K-tiles
    __bf16* BE = lds + ATILE;
    __bf16* AO = lds + DBUFD;         // odd K-tiles
    __bf16* BO = lds + DBUFD + ATILE;

    f32x4 acc[8][4] = {};
    const int NI = FFN / (2 * BKD);   // 32 iterations, 2 K-tiles each

    // prologue: kt0 {A0,A1,B0,B1}, kt1 {B0,B1} = 12 loads; force kt0 (keep 4)
    stageH64(AE,         gA,                           FFN, tid);
    stageH64(AE + AHALF, gA + (size_t)128 * FFN,       FFN, tid);
    stageH64(BE,         gB,                           FFN, tid);
    stageH64(BE + AHALF, gB + (size_t)128 * FFN,       FFN, tid);
    stageH64(BO,         gB + BKD,                     FFN, tid);
    stageH64(BO + AHALF, gB + (size_t)128 * FFN + BKD, FFN, tid);
    asm volatile("s_waitcnt vmcnt(4)" ::: "memory");
    __builtin_amdgcn_s_barrier();

    bf16x8 a[4][2], b[4][2];

    for (int u = 0; u < NI; ++u) {
        const bool pf = (u + 1 < NI);
        const size_t koO = (size_t)(2 * u + 1) * BKD;   // kt 2u+1 (always valid)
        const size_t ko2 = (size_t)(2 * u + 2) * BKD;   // kt 2u+2 (pf)
        const size_t ko3 = (size_t)(2 * u + 3) * BKD;   // kt 2u+3 (pf)

        // ===== ph1: read a03(E)+b01(E) (12); stage A0(2u+1); MFMA Q00(E) ====
#pragma unroll
        for (int i = 0; i < 4; ++i)
#pragma unroll
            for (int ks = 0; ks < 2; ++ks)
                a[i][ks] = ldfrag64(AE, wm * 128 + i * 16 + fr, ks * 4 + fq);
#pragma unroll
        for (int j = 0; j < 2; ++j)
#pragma unroll
            for (int ks = 0; ks < 2; ++ks)
                b[j][ks] = ldfrag64(BE, wn * 64 + j * 16 + fr, ks * 4 + fq);
        stageH64(AO, gA + koO, FFN, tid);
        asm volatile("s_waitcnt lgkmcnt(8)" ::: "memory");
        __builtin_amdgcn_s_barrier();
        asm volatile("s_waitcnt lgkmcnt(0)" ::: "memory");
        __builtin_amdgcn_s_setprio(1);
#pragma unroll
        for (int ks = 0; ks < 2; ++ks)
#pragma unroll
            for (int j = 0; j < 2; ++j)
#pragma unroll
                for (int i = 0; i < 4; ++i)
                    acc[i][j] = __builtin_amdgcn_mfma_f32_16x16x32_bf16(a[i][ks], b[j][ks], acc[i][j], 0, 0, 0);
        __builtin_amdgcn_s_setprio(0);
        __builtin_amdgcn_s_barrier();

        // ===== ph2: read b23(E) (4); stage A1(2u+1); MFMA Q01(E) ====
#pragma unroll
        for (int j = 0; j < 2; ++j)
#pragma unroll
            for (int ks = 0; ks < 2; ++ks)
                b[j + 2][ks] = ldfrag64(BE, wn * 64 + (j + 2) * 16 + fr, ks * 4 + fq);
        stageH64(AO + AHALF, gA + (size_t)128 * FFN + koO, FFN, tid);
        asm volatile("" ::: "memory");
        __builtin_amdgcn_s_barrier();
        asm volatile("s_waitcnt lgkmcnt(0)" ::: "memory");
        __builtin_amdgcn_s_setprio(1);
#pragma unroll
        for (int ks = 0; ks < 2; ++ks)
#pragma unroll
            for (int j = 2; j < 4; ++j)
#pragma unroll
                for (int i = 0; i < 4; ++i)
                    acc[i][j] = __builtin_amdgcn_mfma_f32_16x16x32_bf16(a[i][ks], b[j][ks], acc[i][j], 0, 0, 0);
        __builtin_amdgcn_s_setprio(0);
        __builtin_amdgcn_s_barrier();

        // ===== ph3: read a47(E) (8); stage B0(2u+2); MFMA Q10(E) ====
#pragma unroll
        for (int i = 0; i < 4; ++i)
#pragma unroll
            for (int ks = 0; ks < 2; ++ks)
                a[i][ks] = ldfrag64(AE, wm * 128 + (i + 4) * 16 + fr, ks * 4 + fq);
        if (pf) stageH64(BE, gB + ko2, FFN, tid);
        asm volatile("" ::: "memory");
        __builtin_amdgcn_s_barrier();
        asm volatile("s_waitcnt lgkmcnt(0)" ::: "memory");
        __builtin_amdgcn_s_setprio(1);
#pragma unroll
        for (int ks = 0; ks < 2; ++ks)
#pragma unroll
            for (int j = 0; j < 2; ++j)
#pragma unroll
                for (int i = 0; i < 4; ++i)
                    acc[i + 4][j] = __builtin_amdgcn_mfma_f32_16x16x32_bf16(a[i][ks], b[j][ks], acc[i + 4][j], 0, 0, 0);
        __builtin_amdgcn_s_setprio(0);
        __builtin_amdgcn_s_barrier();

        // ===== ph4: stage B1(2u+2); vmcnt(pf?4:0); MFMA Q11(E) ====
        if (pf) stageH64(BE + AHALF, gB + (size_t)128 * FFN + ko2, FFN, tid);
        if (pf) asm volatile("s_waitcnt vmcnt(4)" ::: "memory");
        else    asm volatile("s_waitcnt vmcnt(0)" ::: "memory");
        asm volatile("" ::: "memory");
        __builtin_amdgcn_s_barrier();
        __builtin_amdgcn_s_setprio(1);
#pragma unroll
        for (int ks = 0; ks < 2; ++ks)
#pragma unroll
            for (int j = 2; j < 4; ++j)
#pragma unroll
                for (int i = 0; i < 4; ++i)
                    acc[i + 4][j] = __builtin_amdgcn_mfma_f32_16x16x32_bf16(a[i][ks], b[j][ks], acc[i + 4][j], 0, 0, 0);
        __builtin_amdgcn_s_setprio(0);
        __builtin_amdgcn_s_barrier();

        // ===== ph5: read a03(O)+b01(O) (12); stage A0(2u+2); MFMA Q00(O) ====
#pragma unroll
        for (int i = 0; i < 4; ++i)
#pragma unroll
            for (int ks = 0; ks < 2; ++ks)
                a[i][ks] = ldfrag64(AO, wm * 128 + i * 16 + fr, ks * 4 + fq);
#pragma unroll
        for (int j = 0; j < 2; ++j)
#pragma unroll
            for (int ks = 0; ks < 2; ++ks)
                b[j][ks] = ldfrag64(BO, wn * 64 + j * 16 + fr, ks * 4 + fq);
        if (pf) stageH64(AE, gA + ko2, FFN, tid);
        asm volatile("s_waitcnt lgkmcnt(8)" ::: "memory");
        __builtin_amdgcn_s_barrier();
        asm volatile("s_waitcnt lgkmcnt(0)" ::: "memory");
        __builtin_amdgcn_s_setprio(1);
#pragma unroll
        for (int ks = 0; ks < 2; ++ks)
#pragma unroll
            for (int j = 0; j < 2; ++j)
#pragma unroll
                for (int i = 0; i < 4; ++i)
                    acc[i][j] = __builtin_amdgcn_mfma_f32_16x16x32_bf16(a[i][ks], b[j][ks], acc[i][j], 0, 0, 0);
        __builtin_amdgcn_s_setprio(0);
        __builtin_amdgcn_s_barrier();

        // ===== ph6: read b23(O) (4); stage A1(2u+2); MFMA Q01(O) ====
#pragma unroll
        for (int j = 0; j < 2; ++j)
#pragma unroll
            for (int ks = 0; ks < 2; ++ks)
                b[j + 2][ks] = ldfrag64(BO, wn * 64 + (j + 2) * 16 + fr, ks * 4 + fq);
        if (pf) stageH64(AE + AHALF, gA + (size_t)128 * FFN + ko2, FFN, tid);
        asm volatile("" ::: "memory");
        __builtin_amdgcn_s_barrier();
        asm volatile("s_waitcnt lgkmcnt(0)" ::: "memory");
        __builtin_amdgcn_s_setprio(1);
#pragma unroll
        for (int ks = 0; ks < 2; ++ks)
#pragma unroll
            for (int j = 2; j < 4; ++j)
#pragma unroll
                for (int i = 0; i < 4; ++i)
                    acc[i][j] = __builtin_amdgcn_mfma_f32_16x16x32_bf16(a[i][ks], b[j][ks], acc[i][j], 0, 0, 0);
        __builtin_amdgcn_s_setprio(0);
        __builtin_amdgcn_s_barrier();

        // ===== ph7: read a47(O) (8); stage B0(2u+3); MFMA Q10(O) ====
#pragma unroll
        for (int i = 0; i < 4; ++i)
#pragma unroll
            for (int ks = 0; ks < 2; ++ks)
                a[i][ks] = ldfrag64(AO, wm * 128 + (i + 4) * 16 + fr, ks * 4 + fq);
        if (pf) stageH64(BO, gB + ko3, FFN, tid);
        asm volatile("" ::: "memory");
        __builtin_amdgcn_s_barrier();
        asm volatile("s_waitcnt lgkmcnt(0)" ::: "memory");
        __builtin_amdgcn_s_setprio(1);
#pragma unroll
        for (int ks = 0; ks < 2; ++ks)
#pragma unroll
            for (int j = 0; j < 2; ++j)
#pragma unroll
                for (int i = 0; i < 4; ++i)
                    acc[i + 4][j] = __builtin_amdgcn_mfma_f32_16x16x32_bf16(a[i][ks], b[j][ks], acc[i + 4][j], 0, 0, 0);
        __builtin_amdgcn_s_setprio(0);
        __builtin_amdgcn_s_barrier();

        // ===== ph8: stage B1(2u+3); vmcnt(4) if pf; MFMA Q11(O) ====
        if (pf) {
            stageH64(BO + AHALF, gB + (size_t)128 * FFN + ko3, FFN, tid);
            asm volatile("s_waitcnt vmcnt(4)" ::: "memory");
        }
        asm volatile("" ::: "memory");
        __builtin_amdgcn_s_barrier();
        __builtin_amdgcn_s_setprio(1);
#pragma unroll
        for (int ks = 0; ks < 2; ++ks)
#pragma unroll
            for (int j = 2; j < 4; ++j)
#pragma unroll
                for (int i = 0; i < 4; ++i)
                    acc[i + 4][j] = __builtin_amdgcn_mfma_f32_16x16x32_bf16(a[i][ks], b[j][ks], acc[i + 4][j], 0, 0, 0);
        __builtin_amdgcn_s_setprio(0);
        __builtin_amdgcn_s_barrier();
    }

    float* gO = out + (size_t)(e * TOK + m0) * HID + n0;
    float bb3[4];
#pragma unroll
    for (int j = 0; j < 4; ++j) bb3[j] = b3[(size_t)e * HID + n0 + wn * 64 + j * 16 + fr];
#pragma unroll
    for (int i = 0; i < 8; ++i) {
#pragma unroll
        for (int r = 0; r < 4; ++r) {
            const int row = wm * 128 + i * 16 + fq * 4 + r;
            const float pp = probs[(size_t)e * TOK + m0 + row];
            float* o = gO + (size_t)row * HID;
#pragma unroll
            for (int j = 0; j < 4; ++j) {
                o[wn * 64 + j * 16 + fr] = (acc[i][j][r] + bb3[j]) * pp;
            }
        }
    }
}

extern "C" void kernel_launch(void* const* d_in, const int* in_sizes, int n_in,
                              void* d_out, int out_size, void* d_ws, size_t ws_size,
                              hipStream_t stream) {
    const float* X     = (const float*)d_in[0];
    // d_in[1] tokens_per_expert (int64): equal split, unused
    const float* probs = (const float*)d_in[2];
    const float* W1    = (const float*)d_in[3];
    const float* b1    = (const float*)d_in[4];
    const float* W2    = (const float*)d_in[5];
    const float* b2    = (const float*)d_in[6];
    const float* W3    = (const float*)d_in[7];
    const float* b3    = (const float*)d_in[8];
    float* out = (float*)d_out;

    const size_t MAT = (size_t)HID * FFN;                  // 8,388,608 elems
    const size_t XBE = (size_t)EXPERTS * TOK * HID;        // 33,554,432 elems
    const size_t slotElems = 4 * MAT;                      // W1T,W2T,W3T,h

    int B = 4;  // measured best; B=8 regressed (r19), B=2 regressed (r7)
    while (B > 1 && ((size_t)B * slotElems + XBE) * sizeof(__bf16) > ws_size) B >>= 1;

    __bf16* wsb = (__bf16*)d_ws;
    __bf16* Xb  = wsb + (size_t)B * slotElems;

    // X -> bf16 once
    cvt_kernel<<<(int)(XBE / 8 / 256), 256, 0, stream>>>(X, Xb, XBE);

    for (int eb = 0; eb < EXPERTS; eb += B) {
        transpose_all_kernel<<<dim3(2048, 3, B), 256, 0, stream>>>(
            W1, W2, W3, wsb, eb, slotElems);

        gateup_kernel<<<dim3(GXU, TOK / BMU, B), 512, 0, stream>>>(
            Xb, wsb, b1, b2, eb, slotElems);
        down_kernel<<<dim3(GXD, TOK / BMD, B), 512, 0, stream>>>(
            wsb, b3, probs, out, eb, slotElems);
    }
}

// Round 25
// 946.164 us; speedup vs baseline: 1.1397x; 1.0337x over previous
//
#include <hip/hip_runtime.h>
#include <hip/hip_bf16.h>

// MoE experts MLP: E=8, T=2048, H=2048, F=4096, fp32 in/out.
// r25: BOTH GEMMs on the 8-PHASE counted-vmcnt template (r24 proved it on
// down: ~200->~179 us, total 998.6->978.0). Gateup becomes a single GEMM
// [T]x[2F] (K=H) via the r21-verified W12 16-col interleave (W1 col f ->
// row (f>>4)*32+(f&15); W2 -> +16), so it is a byte-copy of the working
// 8-phase down kernel (256x256 tile, BK=64, 2 K-tiles/iter, 2x64KiB dbufs,
// per-phase {quadrant ds-reads | stage 1 half-tile | barrier | lgkmcnt(0) |
// setprio 16xMFMA | barrier}, vmcnt(4) only at phases 4+8) with NI=16 and
// r21's thread-local silu epilogue (j-parity: even=gate, odd=up).
// down = r24 verbatim. XCD column grouping, B=4 batching throughout.

#define EXPERTS 8
#define TOK 2048
#define HID 2048
#define FFN 4096

typedef float f32x4 __attribute__((ext_vector_type(4)));
typedef __bf16 bf16x8 __attribute__((ext_vector_type(8)));

#if defined(__has_builtin)
#if __has_builtin(__builtin_amdgcn_global_load_lds)
#define HAVE_GLL 1
#endif
#endif

__device__ __forceinline__ void gload_lds16(const __bf16* g, __bf16* l, int lane) {
#ifdef HAVE_GLL
    __builtin_amdgcn_global_load_lds((const __attribute__((address_space(1))) void*)g,
                                     (__attribute__((address_space(3))) void*)l,
                                     16, 0, 0);
#else
    bf16x8 v = *(const bf16x8*)g;
    *(bf16x8*)(l + lane * 8) = v;
#endif
}

// ---- BK=64 primitives (verified r9/r24: correct + 0 bank conflicts) ----
#define BKD 64
__device__ __forceinline__ bf16x8 ldfrag64(const __bf16* s, int row, int oct) {
    return *(const bf16x8*)(s + row * BKD + ((oct ^ (row & 7)) << 3));
}

// Stage 128x64 half-tile (2 gload_lds / thread, 512 threads), BK=64 layout.
__device__ __forceinline__ void stageH64(__bf16* dst, const __bf16* src, size_t ld, int tid) {
    const int w = tid >> 6, l = tid & 63;
    const int ri = l >> 3, o = l & 7;
#pragma unroll
    for (int q = 0; q < 2; ++q) {
        const int row = q * 64 + w * 8 + ri;
        gload_lds16(src + (size_t)row * ld + ((o ^ ri) << 3),
                    dst + (size_t)(q * 64 + w * 8) * BKD, l);
    }
}

// -------- merged transpose+cvt --------
// m=0: W1 [H][F] -> W12 rows (f>>4)*32+(f&15)    [2F][H]
// m=1: W2 [H][F] -> W12 rows (f>>4)*32+16+(f&15) [2F][H]
// m=2: W3 [F][H] -> W3T [H][F]
__global__ __launch_bounds__(256) void transpose_all_kernel(
    const float* __restrict__ W1, const float* __restrict__ W2,
    const float* __restrict__ W3, __bf16* __restrict__ wsb,
    int e_base, size_t slotElems)
{
    __shared__ float lds[64 * 68];
    const size_t MAT = (size_t)HID * FFN;
    const int t = threadIdx.x;
    const int m = blockIdx.y;
    const int e = e_base + blockIdx.z;

    const float* src;
    __bf16* dst;
    int C, csh;   // src is [R][C]
    if (m == 0)      { src = W1 + (size_t)e * MAT; dst = wsb + (size_t)blockIdx.z * slotElems;           C = FFN; csh = 6; }
    else if (m == 1) { src = W2 + (size_t)e * MAT; dst = wsb + (size_t)blockIdx.z * slotElems;           C = FFN; csh = 6; }
    else             { src = W3 + (size_t)e * MAT; dst = wsb + (size_t)blockIdx.z * slotElems + 2 * MAT; C = HID; csh = 5; }
    const int R = (m == 2) ? FFN : HID;
    const int bx = blockIdx.x & ((1 << csh) - 1);
    const int by = blockIdx.x >> csh;
    const int c0 = bx * 64, r0 = by * 64;

    const int rr = t >> 4;
    const int cc = (t & 15) * 4;
#pragma unroll
    for (int p = 0; p < 4; ++p) {
        const int row = p * 16 + rr;
        f32x4 v = *(const f32x4*)(src + (size_t)(r0 + row) * C + c0 + cc);
        *(f32x4*)&lds[row * 68 + (cc ^ (((row >> 3) & 7) << 2))] = v;
    }
    __syncthreads();
    const int o  = t & 7;
    const int c2 = t >> 3;
#pragma unroll
    for (int q = 0; q < 2; ++q) {
        const int c = q * 32 + c2;
        bf16x8 b;
#pragma unroll
        for (int j = 0; j < 8; ++j) {
            b[j] = (__bf16)lds[(8 * o + j) * 68 + (c ^ (o << 2))];
        }
        const int gcol = c0 + c;
        size_t drow;
        if (m == 2) drow = (size_t)gcol;
        else        drow = (size_t)((gcol >> 4) * 32 + m * 16 + (gcol & 15));
        *(bf16x8*)(dst + drow * R + r0 + 8 * o) = b;
    }
}

// -------- elementwise fp32 -> bf16 --------
__global__ __launch_bounds__(256) void cvt_kernel(const float* __restrict__ src,
                                                  __bf16* __restrict__ dst, size_t n) {
    const size_t i = ((size_t)blockIdx.x * 256 + threadIdx.x) * 8;
    if (i >= n) return;
    f32x4 v0 = *(const f32x4*)(src + i);
    f32x4 v1 = *(const f32x4*)(src + i + 4);
    bf16x8 b;
#pragma unroll
    for (int k = 0; k < 4; ++k) { b[k] = (__bf16)v0[k]; b[4 + k] = (__bf16)v1[k]; }
    *(bf16x8*)(dst + i) = b;
}

// ==== shared 8-phase K-loop macro bits (geometry identical for both GEMMs) ==
#define AHALF (128 * BKD)            // 8192 elems (128x64 half-tile)
#define ATILE (2 * AHALF)            // 16384 elems (256x64)
#define DBUFD (2 * ATILE)            // A + B per dbuf = 32768 elems (64 KiB)

// ---------------- gateup: single GEMM [T]x[2F], K=H, 8-PHASE ----------------
#define BMG 256
#define BNG 256
#define GXG (2 * FFN / BNG)          // 32

__global__ __launch_bounds__(512, 2) void gateup_kernel(
    const __bf16* __restrict__ Xb, const __bf16* __restrict__ wsb,
    const float* __restrict__ b1, const float* __restrict__ b2,
    int e_base, size_t slotElems)
{
    __shared__ __align__(16) __bf16 lds[2 * DBUFD];   // 128 KiB
    const size_t MAT = (size_t)HID * FFN;
    const int tid = threadIdx.x;

    // bijective XCD swizzle (nwg=256); column decomposition: W12 panels pinned.
    int f = blockIdx.y * GXG + blockIdx.x;
    f = (f & 7) * ((GXG * (TOK / BMG)) >> 3) + (f >> 3);
    const int bx = f >> 3;                 // 0..31
    const int by = f & 7;                  // 0..7

    const int e  = e_base + blockIdx.z;
    const int m0 = by * BMG;
    const int n0 = bx * BNG;               // interleaved col base

    const __bf16* base = wsb + (size_t)blockIdx.z * slotElems;
    const __bf16* gA   = Xb + (size_t)(e * TOK + m0) * HID;
    const __bf16* gB   = base + (size_t)n0 * HID;             // W12 [2F][H]

    const int w = tid >> 6, lane = tid & 63;
    const int wm = w >> 2, wn = w & 3;          // 2M x 4N waves, per-wave 128x64
    const int fr = lane & 15, fq = lane >> 4;

    __bf16* AE = lds;
    __bf16* BE = lds + ATILE;
    __bf16* AO = lds + DBUFD;
    __bf16* BO = lds + DBUFD + ATILE;

    f32x4 acc[8][4] = {};
    const int NI = HID / (2 * BKD);   // 16 iterations, 2 K-tiles each

    stageH64(AE,         gA,                           HID, tid);
    stageH64(AE + AHALF, gA + (size_t)128 * HID,       HID, tid);
    stageH64(BE,         gB,                           HID, tid);
    stageH64(BE + AHALF, gB + (size_t)128 * HID,       HID, tid);
    stageH64(BO,         gB + BKD,                     HID, tid);
    stageH64(BO + AHALF, gB + (size_t)128 * HID + BKD, HID, tid);
    asm volatile("s_waitcnt vmcnt(4)" ::: "memory");
    __builtin_amdgcn_s_barrier();

    bf16x8 a[4][2], b[4][2];

    for (int u = 0; u < NI; ++u) {
        const bool pf = (u + 1 < NI);
        const size_t koO = (size_t)(2 * u + 1) * BKD;
        const size_t ko2 = (size_t)(2 * u + 2) * BKD;
        const size_t ko3 = (size_t)(2 * u + 3) * BKD;

        // ===== ph1: read a03(E)+b01(E); stage A0(2u+1); MFMA Q00(E) ====
#pragma unroll
        for (int i = 0; i < 4; ++i)
#pragma unroll
            for (int ks = 0; ks < 2; ++ks)
                a[i][ks] = ldfrag64(AE, wm * 128 + i * 16 + fr, ks * 4 + fq);
#pragma unroll
        for (int j = 0; j < 2; ++j)
#pragma unroll
            for (int ks = 0; ks < 2; ++ks)
                b[j][ks] = ldfrag64(BE, wn * 64 + j * 16 + fr, ks * 4 + fq);
        stageH64(AO, gA + koO, HID, tid);
        asm volatile("s_waitcnt lgkmcnt(8)" ::: "memory");
        __builtin_amdgcn_s_barrier();
        asm volatile("s_waitcnt lgkmcnt(0)" ::: "memory");
        __builtin_amdgcn_s_setprio(1);
#pragma unroll
        for (int ks = 0; ks < 2; ++ks)
#pragma unroll
            for (int j = 0; j < 2; ++j)
#pragma unroll
                for (int i = 0; i < 4; ++i)
                    acc[i][j] = __builtin_amdgcn_mfma_f32_16x16x32_bf16(a[i][ks], b[j][ks], acc[i][j], 0, 0, 0);
        __builtin_amdgcn_s_setprio(0);
        __builtin_amdgcn_s_barrier();

        // ===== ph2: read b23(E); stage A1(2u+1); MFMA Q01(E) ====
#pragma unroll
        for (int j = 0; j < 2; ++j)
#pragma unroll
            for (int ks = 0; ks < 2; ++ks)
                b[j + 2][ks] = ldfrag64(BE, wn * 64 + (j + 2) * 16 + fr, ks * 4 + fq);
        stageH64(AO + AHALF, gA + (size_t)128 * HID + koO, HID, tid);
        asm volatile("" ::: "memory");
        __builtin_amdgcn_s_barrier();
        asm volatile("s_waitcnt lgkmcnt(0)" ::: "memory");
        __builtin_amdgcn_s_setprio(1);
#pragma unroll
        for (int ks = 0; ks < 2; ++ks)
#pragma unroll
            for (int j = 2; j < 4; ++j)
#pragma unroll
                for (int i = 0; i < 4; ++i)
                    acc[i][j] = __builtin_amdgcn_mfma_f32_16x16x32_bf16(a[i][ks], b[j][ks], acc[i][j], 0, 0, 0);
        __builtin_amdgcn_s_setprio(0);
        __builtin_amdgcn_s_barrier();

        // ===== ph3: read a47(E); stage B0(2u+2); MFMA Q10(E) ====
#pragma unroll
        for (int i = 0; i < 4; ++i)
#pragma unroll
            for (int ks = 0; ks < 2; ++ks)
                a[i][ks] = ldfrag64(AE, wm * 128 + (i + 4) * 16 + fr, ks * 4 + fq);
        if (pf) stageH64(BE, gB + ko2, HID, tid);
        asm volatile("" ::: "memory");
        __builtin_amdgcn_s_barrier();
        asm volatile("s_waitcnt lgkmcnt(0)" ::: "memory");
        __builtin_amdgcn_s_setprio(1);
#pragma unroll
        for (int ks = 0; ks < 2; ++ks)
#pragma unroll
            for (int j = 0; j < 2; ++j)
#pragma unroll
                for (int i = 0; i < 4; ++i)
                    acc[i + 4][j] = __builtin_amdgcn_mfma_f32_16x16x32_bf16(a[i][ks], b[j][ks], acc[i + 4][j], 0, 0, 0);
        __builtin_amdgcn_s_setprio(0);
        __builtin_amdgcn_s_barrier();

        // ===== ph4: stage B1(2u+2); vmcnt(pf?4:0); MFMA Q11(E) ====
        if (pf) stageH64(BE + AHALF, gB + (size_t)128 * HID + ko2, HID, tid);
        if (pf) asm volatile("s_waitcnt vmcnt(4)" ::: "memory");
        else    asm volatile("s_waitcnt vmcnt(0)" ::: "memory");
        asm volatile("" ::: "memory");
        __builtin_amdgcn_s_barrier();
        __builtin_amdgcn_s_setprio(1);
#pragma unroll
        for (int ks = 0; ks < 2; ++ks)
#pragma unroll
            for (int j = 2; j < 4; ++j)
#pragma unroll
                for (int i = 0; i < 4; ++i)
                    acc[i + 4][j] = __builtin_amdgcn_mfma_f32_16x16x32_bf16(a[i][ks], b[j][ks], acc[i + 4][j], 0, 0, 0);
        __builtin_amdgcn_s_setprio(0);
        __builtin_amdgcn_s_barrier();

        // ===== ph5: read a03(O)+b01(O); stage A0(2u+2); MFMA Q00(O) ====
#pragma unroll
        for (int i = 0; i < 4; ++i)
#pragma unroll
            for (int ks = 0; ks < 2; ++ks)
                a[i][ks] = ldfrag64(AO, wm * 128 + i * 16 + fr, ks * 4 + fq);
#pragma unroll
        for (int j = 0; j < 2; ++j)
#pragma unroll
            for (int ks = 0; ks < 2; ++ks)
                b[j][ks] = ldfrag64(BO, wn * 64 + j * 16 + fr, ks * 4 + fq);
        if (pf) stageH64(AE, gA + ko2, HID, tid);
        asm volatile("s_waitcnt lgkmcnt(8)" ::: "memory");
        __builtin_amdgcn_s_barrier();
        asm volatile("s_waitcnt lgkmcnt(0)" ::: "memory");
        __builtin_amdgcn_s_setprio(1);
#pragma unroll
        for (int ks = 0; ks < 2; ++ks)
#pragma unroll
            for (int j = 0; j < 2; ++j)
#pragma unroll
                for (int i = 0; i < 4; ++i)
                    acc[i][j] = __builtin_amdgcn_mfma_f32_16x16x32_bf16(a[i][ks], b[j][ks], acc[i][j], 0, 0, 0);
        __builtin_amdgcn_s_setprio(0);
        __builtin_amdgcn_s_barrier();

        // ===== ph6: read b23(O); stage A1(2u+2); MFMA Q01(O) ====
#pragma unroll
        for (int j = 0; j < 2; ++j)
#pragma unroll
            for (int ks = 0; ks < 2; ++ks)
                b[j + 2][ks] = ldfrag64(BO, wn * 64 + (j + 2) * 16 + fr, ks * 4 + fq);
        if (pf) stageH64(AE + AHALF, gA + (size_t)128 * HID + ko2, HID, tid);
        asm volatile("" ::: "memory");
        __builtin_amdgcn_s_barrier();
        asm volatile("s_waitcnt lgkmcnt(0)" ::: "memory");
        __builtin_amdgcn_s_setprio(1);
#pragma unroll
        for (int ks = 0; ks < 2; ++ks)
#pragma unroll
            for (int j = 2; j < 4; ++j)
#pragma unroll
                for (int i = 0; i < 4; ++i)
                    acc[i][j] = __builtin_amdgcn_mfma_f32_16x16x32_bf16(a[i][ks], b[j][ks], acc[i][j], 0, 0, 0);
        __builtin_amdgcn_s_setprio(0);
        __builtin_amdgcn_s_barrier();

        // ===== ph7: read a47(O); stage B0(2u+3); MFMA Q10(O) ====
#pragma unroll
        for (int i = 0; i < 4; ++i)
#pragma unroll
            for (int ks = 0; ks < 2; ++ks)
                a[i][ks] = ldfrag64(AO, wm * 128 + (i + 4) * 16 + fr, ks * 4 + fq);
        if (pf) stageH64(BO, gB + ko3, HID, tid);
        asm volatile("" ::: "memory");
        __builtin_amdgcn_s_barrier();
        asm volatile("s_waitcnt lgkmcnt(0)" ::: "memory");
        __builtin_amdgcn_s_setprio(1);
#pragma unroll
        for (int ks = 0; ks < 2; ++ks)
#pragma unroll
            for (int j = 0; j < 2; ++j)
#pragma unroll
                for (int i = 0; i < 4; ++i)
                    acc[i + 4][j] = __builtin_amdgcn_mfma_f32_16x16x32_bf16(a[i][ks], b[j][ks], acc[i + 4][j], 0, 0, 0);
        __builtin_amdgcn_s_setprio(0);
        __builtin_amdgcn_s_barrier();

        // ===== ph8: stage B1(2u+3); vmcnt(4) if pf; MFMA Q11(O) ====
        if (pf) {
            stageH64(BO + AHALF, gB + (size_t)128 * HID + ko3, HID, tid);
            asm volatile("s_waitcnt vmcnt(4)" ::: "memory");
        }
        asm volatile("" ::: "memory");
        __builtin_amdgcn_s_barrier();
        __builtin_amdgcn_s_setprio(1);
#pragma unroll
        for (int ks = 0; ks < 2; ++ks)
#pragma unroll
            for (int j = 2; j < 4; ++j)
#pragma unroll
                for (int i = 0; i < 4; ++i)
                    acc[i + 4][j] = __builtin_amdgcn_mfma_f32_16x16x32_bf16(a[i][ks], b[j][ks], acc[i + 4][j], 0, 0, 0);
        __builtin_amdgcn_s_setprio(0);
        __builtin_amdgcn_s_barrier();
    }

    // epilogue (r21-verified): j even = gate, j odd = up; f = n0/2 + wn*32 +
    // (j>>1)*16 + fr; rows wm*128 + i*16 + fq*4 + r.
    __bf16* gH = (__bf16*)(base + 3 * MAT) + (size_t)m0 * FFN;
    const int fb = (n0 >> 1) + wn * 32;
#pragma unroll
    for (int p = 0; p < 2; ++p) {
        const int fcol = fb + p * 16 + fr;
        const float bb1 = b1[(size_t)e * FFN + fcol];
        const float bb2 = b2[(size_t)e * FFN + fcol];
#pragma unroll
        for (int i = 0; i < 8; ++i) {
#pragma unroll
            for (int r = 0; r < 4; ++r) {
                const int row = wm * 128 + i * 16 + fq * 4 + r;
                const float g = acc[i][2 * p][r] + bb1;
                const float u = acc[i][2 * p + 1][r] + bb2;
                const float s = g / (1.0f + __expf(-g));
                gH[(size_t)row * FFN + fcol] = (__bf16)(s * u);
            }
        }
    }
}

// ---------------- down: GEMM 256x256, BK=64, 8-PHASE (r24 verbatim) ---------
#define BMD 256
#define BND 256
#define GXD (HID / BND)              // 8

__global__ __launch_bounds__(512, 2) void down_kernel(
    const __bf16* __restrict__ wsb, const float* __restrict__ b3,
    const float* __restrict__ probs, float* __restrict__ out,
    int e_base, size_t slotElems)
{
    __shared__ __align__(16) __bf16 lds[2 * DBUFD];   // 128 KiB
    const size_t MAT = (size_t)HID * FFN;
    const int tid = threadIdx.x;

    int f = blockIdx.y * GXD + blockIdx.x;
    f = (f & 7) * ((GXD * (TOK / BMD)) >> 3) + (f >> 3);
    const int bx = f >> 3;                 // 0..7
    const int by = f & 7;                  // 0..7

    const int e  = e_base + blockIdx.z;
    const int m0 = by * BMD;
    const int n0 = bx * BND;

    const __bf16* base = wsb + (size_t)blockIdx.z * slotElems;
    const __bf16* gA   = base + 3 * MAT + (size_t)m0 * FFN;   // h [T][F]
    const __bf16* gB   = base + 2 * MAT + (size_t)n0 * FFN;   // W3T [H][F]

    const int w = tid >> 6, lane = tid & 63;
    const int wm = w >> 2, wn = w & 3;
    const int fr = lane & 15, fq = lane >> 4;

    __bf16* AE = lds;
    __bf16* BE = lds + ATILE;
    __bf16* AO = lds + DBUFD;
    __bf16* BO = lds + DBUFD + ATILE;

    f32x4 acc[8][4] = {};
    const int NI = FFN / (2 * BKD);   // 32

    stageH64(AE,         gA,                           FFN, tid);
    stageH64(AE + AHALF, gA + (size_t)128 * FFN,       FFN, tid);
    stageH64(BE,         gB,                           FFN, tid);
    stageH64(BE + AHALF, gB + (size_t)128 * FFN,       FFN, tid);
    stageH64(BO,         gB + BKD,                     FFN, tid);
    stageH64(BO + AHALF, gB + (size_t)128 * FFN + BKD, FFN, tid);
    asm volatile("s_waitcnt vmcnt(4)" ::: "memory");
    __builtin_amdgcn_s_barrier();

    bf16x8 a[4][2], b[4][2];

    for (int u = 0; u < NI; ++u) {
        const bool pf = (u + 1 < NI);
        const size_t koO = (size_t)(2 * u + 1) * BKD;
        const size_t ko2 = (size_t)(2 * u + 2) * BKD;
        const size_t ko3 = (size_t)(2 * u + 3) * BKD;

#pragma unroll
        for (int i = 0; i < 4; ++i)
#pragma unroll
            for (int ks = 0; ks < 2; ++ks)
                a[i][ks] = ldfrag64(AE, wm * 128 + i * 16 + fr, ks * 4 + fq);
#pragma unroll
        for (int j = 0; j < 2; ++j)
#pragma unroll
            for (int ks = 0; ks < 2; ++ks)
                b[j][ks] = ldfrag64(BE, wn * 64 + j * 16 + fr, ks * 4 + fq);
        stageH64(AO, gA + koO, FFN, tid);
        asm volatile("s_waitcnt lgkmcnt(8)" ::: "memory");
        __builtin_amdgcn_s_barrier();
        asm volatile("s_waitcnt lgkmcnt(0)" ::: "memory");
        __builtin_amdgcn_s_setprio(1);
#pragma unroll
        for (int ks = 0; ks < 2; ++ks)
#pragma unroll
            for (int j = 0; j < 2; ++j)
#pragma unroll
                for (int i = 0; i < 4; ++i)
                    acc[i][j] = __builtin_amdgcn_mfma_f32_16x16x32_bf16(a[i][ks], b[j][ks], acc[i][j], 0, 0, 0);
        __builtin_amdgcn_s_setprio(0);
        __builtin_amdgcn_s_barrier();

#pragma unroll
        for (int j = 0; j < 2; ++j)
#pragma unroll
            for (int ks = 0; ks < 2; ++ks)
                b[j + 2][ks] = ldfrag64(BE, wn * 64 + (j + 2) * 16 + fr, ks * 4 + fq);
        stageH64(AO + AHALF, gA + (size_t)128 * FFN + koO, FFN, tid);
        asm volatile("" ::: "memory");
        __builtin_amdgcn_s_barrier();
        asm volatile("s_waitcnt lgkmcnt(0)" ::: "memory");
        __builtin_amdgcn_s_setprio(1);
#pragma unroll
        for (int ks = 0; ks < 2; ++ks)
#pragma unroll
            for (int j = 2; j < 4; ++j)
#pragma unroll
                for (int i = 0; i < 4; ++i)
                    acc[i][j] = __builtin_amdgcn_mfma_f32_16x16x32_bf16(a[i][ks], b[j][ks], acc[i][j], 0, 0, 0);
        __builtin_amdgcn_s_setprio(0);
        __builtin_amdgcn_s_barrier();

#pragma unroll
        for (int i = 0; i < 4; ++i)
#pragma unroll
            for (int ks = 0; ks < 2; ++ks)
                a[i][ks] = ldfrag64(AE, wm * 128 + (i + 4) * 16 + fr, ks * 4 + fq);
        if (pf) stageH64(BE, gB + ko2, FFN, tid);
        asm volatile("" ::: "memory");
        __builtin_amdgcn_s_barrier();
        asm volatile("s_waitcnt lgkmcnt(0)" ::: "memory");
        __builtin_amdgcn_s_setprio(1);
#pragma unroll
        for (int ks = 0; ks < 2; ++ks)
#pragma unroll
            for (int j = 0; j < 2; ++j)
#pragma unroll
                for (int i = 0; i < 4; ++i)
                    acc[i + 4][j] = __builtin_amdgcn_mfma_f32_16x16x32_bf16(a[i][ks], b[j][ks], acc[i + 4][j], 0, 0, 0);
        __builtin_amdgcn_s_setprio(0);
        __builtin_amdgcn_s_barrier();

        if (pf) stageH64(BE + AHALF, gB + (size_t)128 * FFN + ko2, FFN, tid);
        if (pf) asm volatile("s_waitcnt vmcnt(4)" ::: "memory");
        else    asm volatile("s_waitcnt vmcnt(0)" ::: "memory");
        asm volatile("" ::: "memory");
        __builtin_amdgcn_s_barrier();
        __builtin_amdgcn_s_setprio(1);
#pragma unroll
        for (int ks = 0; ks < 2; ++ks)
#pragma unroll
            for (int j = 2; j < 4; ++j)
#pragma unroll
                for (int i = 0; i < 4; ++i)
                    acc[i + 4][j] = __builtin_amdgcn_mfma_f32_16x16x32_bf16(a[i][ks], b[j][ks], acc[i + 4][j], 0, 0, 0);
        __builtin_amdgcn_s_setprio(0);
        __builtin_amdgcn_s_barrier();

#pragma unroll
        for (int i = 0; i < 4; ++i)
#pragma unroll
            for (int ks = 0; ks < 2; ++ks)
                a[i][ks] = ldfrag64(AO, wm * 128 + i * 16 + fr, ks * 4 + fq);
#pragma unroll
        for (int j = 0; j < 2; ++j)
#pragma unroll
            for (int ks = 0; ks < 2; ++ks)
                b[j][ks] = ldfrag64(BO, wn * 64 + j * 16 + fr, ks * 4 + fq);
        if (pf) stageH64(AE, gA + ko2, FFN, tid);
        asm volatile("s_waitcnt lgkmcnt(8)" ::: "memory");
        __builtin_amdgcn_s_barrier();
        asm volatile("s_waitcnt lgkmcnt(0)" ::: "memory");
        __builtin_amdgcn_s_setprio(1);
#pragma unroll
        for (int ks = 0; ks < 2; ++ks)
#pragma unroll
            for (int j = 0; j < 2; ++j)
#pragma unroll
                for (int i = 0; i < 4; ++i)
                    acc[i][j] = __builtin_amdgcn_mfma_f32_16x16x32_bf16(a[i][ks], b[j][ks], acc[i][j], 0, 0, 0);
        __builtin_amdgcn_s_setprio(0);
        __builtin_amdgcn_s_barrier();

#pragma unroll
        for (int j = 0; j < 2; ++j)
#pragma unroll
            for (int ks = 0; ks < 2; ++ks)
                b[j + 2][ks] = ldfrag64(BO, wn * 64 + (j + 2) * 16 + fr, ks * 4 + fq);
        if (pf) stageH64(AE + AHALF, gA + (size_t)128 * FFN + ko2, FFN, tid);
        asm volatile("" ::: "memory");
        __builtin_amdgcn_s_barrier();
        asm volatile("s_waitcnt lgkmcnt(0)" ::: "memory");
        __builtin_amdgcn_s_setprio(1);
#pragma unroll
        for (int ks = 0; ks < 2; ++ks)
#pragma unroll
            for (int j = 2; j < 4; ++j)
#pragma unroll
                for (int i = 0; i < 4; ++i)
                    acc[i][j] = __builtin_amdgcn_mfma_f32_16x16x32_bf16(a[i][ks], b[j][ks], acc[i][j], 0, 0, 0);
        __builtin_amdgcn_s_setprio(0);
        __builtin_amdgcn_s_barrier();

#pragma unroll
        for (int i = 0; i < 4; ++i)
#pragma unroll
            for (int ks = 0; ks < 2; ++ks)
                a[i][ks] = ldfrag64(AO, wm * 128 + (i + 4) * 16 + fr, ks * 4 + fq);
        if (pf) stageH64(BO, gB + ko3, FFN, tid);
        asm volatile("" ::: "memory");
        __builtin_amdgcn_s_barrier();
        asm volatile("s_waitcnt lgkmcnt(0)" ::: "memory");
        __builtin_amdgcn_s_setprio(1);
#pragma unroll
        for (int ks = 0; ks < 2; ++ks)
#pragma unroll
            for (int j = 0; j < 2; ++j)
#pragma unroll
                for (int i = 0; i < 4; ++i)
                    acc[i + 4][j] = __builtin_amdgcn_mfma_f32_16x16x32_bf16(a[i][ks], b[j][ks], acc[i + 4][j], 0, 0, 0);
        __builtin_amdgcn_s_setprio(0);
        __builtin_amdgcn_s_barrier();

        if (pf) {
            stageH64(BO + AHALF, gB + (size_t)128 * FFN + ko3, FFN, tid);
            asm volatile("s_waitcnt vmcnt(4)" ::: "memory");
        }
        asm volatile("" ::: "memory");
        __builtin_amdgcn_s_barrier();
        __builtin_amdgcn_s_setprio(1);
#pragma unroll
        for (int ks = 0; ks < 2; ++ks)
#pragma unroll
            for (int j = 2; j < 4; ++j)
#pragma unroll
                for (int i = 0; i < 4; ++i)
                    acc[i + 4][j] = __builtin_amdgcn_mfma_f32_16x16x32_bf16(a[i][ks], b[j][ks], acc[i + 4][j], 0, 0, 0);
        __builtin_amdgcn_s_setprio(0);
        __builtin_amdgcn_s_barrier();
    }

    float* gO = out + (size_t)(e * TOK + m0) * HID + n0;
    float bb3[4];
#pragma unroll
    for (int j = 0; j < 4; ++j) bb3[j] = b3[(size_t)e * HID + n0 + wn * 64 + j * 16 + fr];
#pragma unroll
    for (int i = 0; i < 8; ++i) {
#pragma unroll
        for (int r = 0; r < 4; ++r) {
            const int row = wm * 128 + i * 16 + fq * 4 + r;
            const float pp = probs[(size_t)e * TOK + m0 + row];
            float* o = gO + (size_t)row * HID;
#pragma unroll
            for (int j = 0; j < 4; ++j) {
                o[wn * 64 + j * 16 + fr] = (acc[i][j][r] + bb3[j]) * pp;
            }
        }
    }
}

extern "C" void kernel_launch(void* const* d_in, const int* in_sizes, int n_in,
                              void* d_out, int out_size, void* d_ws, size_t ws_size,
                              hipStream_t stream) {
    const float* X     = (const float*)d_in[0];
    // d_in[1] tokens_per_expert (int64): equal split, unused
    const float* probs = (const float*)d_in[2];
    const float* W1    = (const float*)d_in[3];
    const float* b1    = (const float*)d_in[4];
    const float* W2    = (const float*)d_in[5];
    const float* b2    = (const float*)d_in[6];
    const float* W3    = (const float*)d_in[7];
    const float* b3    = (const float*)d_in[8];
    float* out = (float*)d_out;

    const size_t MAT = (size_t)HID * FFN;                  // 8,388,608 elems
    const size_t XBE = (size_t)EXPERTS * TOK * HID;        // 33,554,432 elems
    const size_t slotElems = 4 * MAT;                      // W12(2), W3T, h

    int B = 4;  // measured best; B=8 regressed (r19), B=2 regressed (r7)
    while (B > 1 && ((size_t)B * slotElems + XBE) * sizeof(__bf16) > ws_size) B >>= 1;

    __bf16* wsb = (__bf16*)d_ws;
    __bf16* Xb  = wsb + (size_t)B * slotElems;

    // X -> bf16 once
    cvt_kernel<<<(int)(XBE / 8 / 256), 256, 0, stream>>>(X, Xb, XBE);

    for (int eb = 0; eb < EXPERTS; eb += B) {
        transpose_all_kernel<<<dim3(2048, 3, B), 256, 0, stream>>>(
            W1, W2, W3, wsb, eb, slotElems);

        gateup_kernel<<<dim3(GXG, TOK / BMG, B), 512, 0, stream>>>(
            Xb, wsb, b1, b2, eb, slotElems);
        down_kernel<<<dim3(GXD, TOK / BMD, B), 512, 0, stream>>>(
            wsb, b3, probs, out, eb, slotElems);
    }
}